// Round 13
// baseline (539.527 us; speedup 1.0000x reference)
//
#include <hip/hip_runtime.h>

// WindowAttention for MI355X (gfx950) — round 13.
// R11 host (proven 300us) + A-panel direct-to-register:
//  - xs stored UNSWIZZLED; each lane global-loads its 8 A-fragments per kt
//    straight to VGPR (wave's 64 rows are wave-private -> no LDS transit).
//  - LDS stage = B only (12KB, 3 gloads/thread); barriers unchanged.
//  - R12's null levers (setprio, q/k scatter swizzle) reverted.
//  prepN / proj: proven structure (prepN drops the x-copy XOR only).
// Fallback: R2 path if ws too small.

typedef __bf16 bf16x8 __attribute__((ext_vector_type(8)));
typedef float f32x4 __attribute__((ext_vector_type(4)));

#define SCALE_Q 0.17677669529663687f

// ---- ws layout (bytes), new path ----
//  [0,        1572864)    wqkv_f  bf16 [1536][512], row c = head*96+which*32+d
//  [1572864,  2097152)    wproj_f bf16 [512][512] row-major
//  [2097152,  2359296)    bias_f  f32 [16][64][64], -1e30 pads
//  [2359296,  2365440)    qkvb_r  f32 [1536] reordered (head,which,d)
//  [2365440,  136583168)  xs      bf16 [131072][512] padded, UNSWIZZLED
//  [136583168,239343616)  attnout bf16 [100352][512] compact
#define OFF_XS     2365440ull
#define OFF_ATTN   136583168ull
#define WS2        507779072ull
#define WS_R2      105119744ull

// native RNE f32->bf16 (compiler emits v_cvt_pk_bf16_f32 for pairs)
__device__ __forceinline__ unsigned short bfc(float f) {
    union { __bf16 b; unsigned short u; } x; x.b = (__bf16)f; return x.u;
}

__device__ __forceinline__ uint4 cvt8(const float f[8]) {
    uint4 p;
    p.x = (unsigned)bfc(f[0]) | ((unsigned)bfc(f[1]) << 16);
    p.y = (unsigned)bfc(f[2]) | ((unsigned)bfc(f[3]) << 16);
    p.z = (unsigned)bfc(f[4]) | ((unsigned)bfc(f[5]) << 16);
    p.w = (unsigned)bfc(f[6]) | ((unsigned)bfc(f[7]) << 16);
    return p;
}

__device__ __forceinline__ unsigned short f2bf(float f) {
    unsigned int u = __float_as_uint(f);
    u += 0x7FFFu + ((u >> 16) & 1u);
    return (unsigned short)(u >> 16);
}

__device__ __forceinline__ uint4 pack8(const unsigned short o[8]) {
    uint4 p;
    p.x = (unsigned)o[0] | ((unsigned)o[1] << 16);
    p.y = (unsigned)o[2] | ((unsigned)o[3] << 16);
    p.z = (unsigned)o[4] | ((unsigned)o[5] << 16);
    p.w = (unsigned)o[6] | ((unsigned)o[7] << 16);
    return p;
}

union BU8 { bf16x8 v; unsigned short s[8]; };

#define GLOAD16(g, l) __builtin_amdgcn_global_load_lds( \
    (__attribute__((address_space(1))) void*)(void*)(g), \
    (__attribute__((address_space(3))) void*)(l), 16, 0, 0)

// ================= prepN =================
__global__ void prepN_kernel(const float* __restrict__ x,
                             const float* __restrict__ qkv_w,
                             const float* __restrict__ qkv_b,
                             const float* __restrict__ proj_w,
                             const float* __restrict__ bias_table,
                             unsigned short* __restrict__ wqkv_f,
                             unsigned short* __restrict__ wproj_f,
                             float* __restrict__ bias_f,
                             float* __restrict__ qkvb_r,
                             unsigned short* __restrict__ xs) {
    int b = blockIdx.x, t = threadIdx.x;
    if (b < 384) {
        // wqkv_f[c][k], c = head*96 + which*32 + d  <-  qkv_w[head*96+d*3+which]
        int gid = b * 256 + t;              // 98304 = 1536*64
        int c = gid >> 6, k8 = (gid & 63) * 8;
        int head = c / 96, rem = c - head * 96;
        int which = rem >> 5, d = rem & 31;
        const float* src = qkv_w + (size_t)(head * 96 + d * 3 + which) * 512 + k8;
        float f[8];
#pragma unroll
        for (int j = 0; j < 8; ++j) f[j] = src[j];
        *(uint4*)(wqkv_f + (size_t)c * 512 + k8) = cvt8(f);
    } else if (b < 512) {
        int gid = (b - 384) * 256 + t;      // 32768 * 8 = 512*512
        const float* src = proj_w + (size_t)gid * 8;
        float f[8];
#pragma unroll
        for (int j = 0; j < 8; ++j) f[j] = src[j];
        *(uint4*)(wproj_f + (size_t)gid * 8) = cvt8(f);
    } else if (b < 768) {
        int gid = (b - 512) * 256 + t;      // 65536
        int j = gid & 63; int i = (gid >> 6) & 63; int h = gid >> 12;
        float v = -1e30f;
        if (i < 49 && j < 49) {
            int ri = i / 7, ci = i % 7, rj = j / 7, cj = j % 7;
            int idx = (ri - rj + 6) * 13 + (ci - cj + 6);
            v = bias_table[idx * 16 + h];
        }
        bias_f[gid] = v;
    } else if (b == 768) {
        for (int c = t; c < 1536; c += 256) {
            int head = c / 96, rem = c - head * 96;
            int which = rem >> 5, d = rem & 31;
            qkvb_r[c] = qkv_b[head * 96 + d * 3 + which];
        }
    } else {
        // x -> bf16 PADDED [131072][512], UNSWIZZLED (A-frags read direct).
        int gid = (b - 769) * 256 + t;      // < 1048576 = 131072*8
        int row = gid >> 3, kt = gid & 7;
        int win = row >> 6, tok = row & 63; if (tok > 48) tok = 48;
        const float* src = x + ((size_t)win * 49 + tok) * 512 + kt * 64;
        unsigned short* dst = xs + (size_t)row * 512 + kt * 64;
#pragma unroll
        for (int c = 0; c < 8; ++c) {
            float f[8];
            *(float4*)&f[0] = *(const float4*)(src + c * 8);
            *(float4*)&f[4] = *(const float4*)(src + c * 8 + 4);
            *(uint4*)(dst + c * 8) = cvt8(f);
        }
    }
}

// ================= K1: fused QKV GEMM + attention =================
// block = (mb: 4 windows, head), 256 threads / 4 waves, wave = 64 M-rows.
// A-panel: direct global->reg per-lane fragment loads (no LDS transit).
// LDS (49152 B total, time-overlaid):
//  GEMM phase:  B stage [0,12288) = [96][128B swz]
//  post-GEMM:   qkv [0,49152) = 4 win x {q[64][32],k[64][32],vt[32][64]} (12KB ea)
//               P (8KB/wave) overlays wave's OWN window's dead q+k
__global__ __launch_bounds__(256, 3)
void qkvattn_kernel(const unsigned short* __restrict__ xs,
                    const unsigned short* __restrict__ wqkv_f,
                    const float* __restrict__ qkvb_r,
                    const float* __restrict__ bias_f,
                    unsigned short* __restrict__ attnout) {
    __shared__ __align__(16) char smem[49152];
    char* Bs = smem;                       // B stage; dead after GEMM loop

    // XCD swizzle: 8192 blocks = 8 * 1024; head-inner within an XCD.
    int i = blockIdx.x;
    int virt = (i & 7) * 1024 + (i >> 3);
    int mb = virt >> 4, head = virt & 15;   // mb: 0..511 (4 windows each)
    int m0 = mb * 256;

    const int tid = threadIdx.x;
    const int l = tid & 63;
    const int W = tid >> 6;
    const int lr = l & 15;
    const int lg = l >> 4;

    f32x4 acc[4][6];
    const f32x4 zf = {0.f, 0.f, 0.f, 0.f};
#pragma unroll
    for (int mt = 0; mt < 4; ++mt)
#pragma unroll
        for (int nt = 0; nt < 6; ++nt) acc[mt][nt] = zf;

    int rsub = l >> 3, csub = l & 7;
    int cswz = (csub ^ rsub) * 16;         // B runtime inverse-swizzle

    const char* bbase = (const char*)wqkv_f + (size_t)head * 96 * 1024;
    // per-lane A base: this lane's rows are (m0 + W*64 + mt*16 + lr)
    const unsigned short* apане_unused = nullptr; (void)apане_unused;
    const unsigned short* abase = xs + (size_t)(m0 + W * 64 + lr) * 512 + lg * 8;

#pragma unroll 1
    for (int kt = 0; kt < 8; ++kt) {
        int ko = kt * 128;                 // byte offset of k-tile (64 bf16)
        // A fragments: direct global->reg (8 x 16B per lane)
        bf16x8 af[4][2];
#pragma unroll
        for (int mt = 0; mt < 4; ++mt)
#pragma unroll
            for (int ks = 0; ks < 2; ++ks)
                af[mt][ks] = *(const bf16x8*)(abase +
                    (size_t)(mt * 16) * 512 + kt * 64 + ks * 32);
        // B: 96 rows x 128B; 3 loads/thread
#pragma unroll
        for (int jj = 0; jj < 3; ++jj) {
            int r = jj * 32 + W * 8 + rsub;
            GLOAD16(bbase + (size_t)r * 1024 + ko + cswz, Bs + jj * 4096 + W * 1024);
        }
        __syncthreads();
#pragma unroll
        for (int ks = 0; ks < 2; ++ks) {
            bf16x8 bf[6];
#pragma unroll
            for (int nt = 0; nt < 6; ++nt) {
                int row = nt * 16 + lr;
                bf[nt] = *(const bf16x8*)(Bs + row * 128 +
                    ((ks * 64 + lg * 16) ^ ((row & 7) << 4)));
            }
#pragma unroll
            for (int mt = 0; mt < 4; ++mt)
#pragma unroll
                for (int nt = 0; nt < 6; ++nt)
                    acc[mt][nt] = __builtin_amdgcn_mfma_f32_16x16x32_bf16(
                        af[mt][ks], bf[nt], acc[mt][nt], 0, 0, 0);
        }
        __syncthreads();
    }

    // ---- scatter acc -> qkv LDS (overlays dead B stage) ----
    // wave W owns window W: all 64 toks x 96 cols -> wave-local from here on.
    unsigned short* wbuf = (unsigned short*)smem + W * 6144;
    {
        int tokb = 4 * lg;
#pragma unroll
        for (int nt = 0; nt < 6; ++nt) {
            const int which = nt >> 1;
            const int d = (nt & 1) * 16 + lr;
            float bias = qkvb_r[head * 96 + which * 32 + d];
            float sc = (which == 0) ? SCALE_Q : 1.0f;
#pragma unroll
            for (int mt = 0; mt < 4; ++mt) {
                int tok0 = tokb + mt * 16;
                if (which == 2) {
                    // vt[d][tok], tok-chunk XOR swizzle; 4 toks in one chunk
                    int idx = 4096 + d * 64 + (((tok0 >> 3) ^ (d & 7)) << 3) + (tok0 & 7);
                    ushort4 u;
                    u.x = bfc(acc[mt][nt][0] + bias);
                    u.y = bfc(acc[mt][nt][1] + bias);
                    u.z = bfc(acc[mt][nt][2] + bias);
                    u.w = bfc(acc[mt][nt][3] + bias);
                    *(ushort4*)(wbuf + idx) = u;
                } else {
#pragma unroll
                    for (int r = 0; r < 4; ++r)
                        wbuf[which * 2048 + (tok0 + r) * 32 + d] =
                            bfc((acc[mt][nt][r] + bias) * sc);
                }
            }
        }
    }
    // no barrier: attention below is entirely wave-local (wave = its window)

    // ---- attention: wave W = window W (64 q rows), barrier-free ----
    {
        const unsigned short* qa = wbuf;
        char* P = smem + W * 12288;         // 8KB, overlays own dead q+k
        int win_g = mb * 4 + W;
        unsigned short* ao = attnout + (size_t)win_g * (49 * 512);

        bf16x8 qf[4], kf[4], vf[2][2];
#pragma unroll
        for (int i2 = 0; i2 < 4; ++i2) {
            qf[i2] = *(const bf16x8*)(qa + (i2 * 16 + lr) * 32 + lg * 8);
            kf[i2] = *(const bf16x8*)(qa + 2048 + (i2 * 16 + lr) * 32 + lg * 8);
        }
#pragma unroll
        for (int ks = 0; ks < 2; ++ks)
#pragma unroll
            for (int nt = 0; nt < 2; ++nt) {
                int d = nt * 16 + lr;
                vf[ks][nt] = *(const bf16x8*)(qa + 4096 + d * 64 +
                    (((ks * 4 + lg) ^ (d & 7)) << 3));
            }

        // S^T[kv][q]
        f32x4 s[4][4];
#pragma unroll
        for (int mt = 0; mt < 4; ++mt)
#pragma unroll
            for (int qt = 0; qt < 4; ++qt)
                s[mt][qt] = __builtin_amdgcn_mfma_f32_16x16x32_bf16(
                    kf[mt], qf[qt], zf, 0, 0, 0);
        // bias (kv pads = -1e30)
#pragma unroll
        for (int qt = 0; qt < 4; ++qt) {
            int q = qt * 16 + lr;
            const float* bb = bias_f + ((size_t)head * 64 + q) * 64;
#pragma unroll
            for (int mt = 0; mt < 4; ++mt) {
                float4 b4 = *(const float4*)(bb + mt * 16 + lg * 4);
                s[mt][qt][0] += b4.x; s[mt][qt][1] += b4.y;
                s[mt][qt][2] += b4.z; s[mt][qt][3] += b4.w;
            }
        }
        // softmax per q column; P -> LDS bf16 (overwrites own q/k — reads done)
#pragma unroll
        for (int qt = 0; qt < 4; ++qt) {
            float m = -1e30f;
#pragma unroll
            for (int mt = 0; mt < 4; ++mt)
#pragma unroll
                for (int r = 0; r < 4; ++r) m = fmaxf(m, s[mt][qt][r]);
            m = fmaxf(m, __shfl_xor(m, 16));
            m = fmaxf(m, __shfl_xor(m, 32));
            float sum = 0.f;
#pragma unroll
            for (int mt = 0; mt < 4; ++mt)
#pragma unroll
                for (int r = 0; r < 4; ++r) {
                    float p = __expf(s[mt][qt][r] - m);
                    s[mt][qt][r] = p; sum += p;
                }
            sum += __shfl_xor(sum, 16);
            sum += __shfl_xor(sum, 32);
            float inv = 1.0f / sum;
            int ql = qt * 16 + lr;          // 0..63
            int sw = (ql & 7) << 4;
#pragma unroll
            for (int mt = 0; mt < 4; ++mt) {
                uint2 uv;
                uv.x = (unsigned)bfc(s[mt][qt][0] * inv) |
                       ((unsigned)bfc(s[mt][qt][1] * inv) << 16);
                uv.y = (unsigned)bfc(s[mt][qt][2] * inv) |
                       ((unsigned)bfc(s[mt][qt][3] * inv) << 16);
                *(uint2*)(P + ql * 128 + ((mt * 32 + lg * 8) ^ sw)) = uv;
            }
        }
        // PV
        f32x4 o[4][2];
#pragma unroll
        for (int mt = 0; mt < 4; ++mt) {
            o[mt][0] = zf; o[mt][1] = zf;
            int ql = mt * 16 + lr;
            int sw = (ql & 7) << 4;
#pragma unroll
            for (int ks = 0; ks < 2; ++ks) {
                bf16x8 pf = *(const bf16x8*)(P + ql * 128 + ((ks * 64 + lg * 16) ^ sw));
                o[mt][0] = __builtin_amdgcn_mfma_f32_16x16x32_bf16(pf, vf[ks][0], o[mt][0], 0, 0, 0);
                o[mt][1] = __builtin_amdgcn_mfma_f32_16x16x32_bf16(pf, vf[ks][1], o[mt][1], 0, 0, 0);
            }
        }
#pragma unroll
        for (int mt = 0; mt < 4; ++mt)
#pragma unroll
            for (int nt = 0; nt < 2; ++nt)
#pragma unroll
                for (int r = 0; r < 4; ++r) {
                    int q = mt * 16 + 4 * lg + r;
                    if (q < 49)
                        ao[q * 512 + head * 32 + nt * 16 + lr] = bfc(o[mt][nt][r]);
                }
    }
}

// ================= K3: proj GEMM (unchanged, proven) =================
__global__ __launch_bounds__(256, 2)
void proj_kernel(const unsigned short* __restrict__ attnout,
                 const unsigned short* __restrict__ wproj_f,
                 const float* __restrict__ proj_b,
                 float* __restrict__ out) {
    __shared__ __align__(16) char smem[32768];
    char* As = smem;
    char* Bs = smem + 16384;

    int bid = blockIdx.x;
    int c = bid >> 2;
    int cs = (c & 7) * 98 + (c >> 3);
    int m0 = cs * 128;
    int n0 = (bid & 3) * 128;

    const int tid = threadIdx.x;
    const int l = tid & 63;
    const int W = tid >> 6;
    const int lr = l & 15;
    const int lg = l >> 4;
    const int Wm = W >> 1, Wn = W & 1;

    f32x4 acc[4][4];
    const f32x4 zf = {0.f, 0.f, 0.f, 0.f};
#pragma unroll
    for (int mt = 0; mt < 4; ++mt)
#pragma unroll
        for (int nt = 0; nt < 4; ++nt) acc[mt][nt] = zf;

    int rsub = l >> 3;
    int csub = l & 7;
    int cswz = (csub ^ rsub) * 16;

#pragma unroll 1
    for (int kt = 0; kt < 8; ++kt) {
#pragma unroll
        for (int i = 0; i < 4; ++i) {
            int r = i * 32 + W * 8 + rsub;
            const char* srcA = (const char*)attnout +
                ((size_t)(m0 + r) * 512 + kt * 64) * 2 + cswz;
            GLOAD16(srcA, As + i * 4096 + W * 1024);
            const char* srcB = (const char*)wproj_f +
                ((size_t)(n0 + r) * 512 + kt * 64) * 2 + cswz;
            GLOAD16(srcB, Bs + i * 4096 + W * 1024);
        }
        __syncthreads();
#pragma unroll
        for (int ks = 0; ks < 2; ++ks) {
            bf16x8 af[4], bf[4];
#pragma unroll
            for (int mt = 0; mt < 4; ++mt) {
                int row = Wm * 64 + mt * 16 + lr;
                af[mt] = *(const bf16x8*)(As + row * 128 +
                    ((ks * 64 + lg * 16) ^ ((row & 7) << 4)));
            }
#pragma unroll
            for (int nt = 0; nt < 4; ++nt) {
                int row = Wn * 64 + nt * 16 + lr;
                bf[nt] = *(const bf16x8*)(Bs + row * 128 +
                    ((ks * 64 + lg * 16) ^ ((row & 7) << 4)));
            }
#pragma unroll
            for (int mt = 0; mt < 4; ++mt)
#pragma unroll
                for (int nt = 0; nt < 4; ++nt)
                    acc[mt][nt] = __builtin_amdgcn_mfma_f32_16x16x32_bf16(
                        af[mt], bf[nt], acc[mt][nt], 0, 0, 0);
        }
        __syncthreads();
    }
#pragma unroll
    for (int nt = 0; nt < 4; ++nt) {
        int n = n0 + Wn * 64 + nt * 16 + lr;
        float pb = proj_b[n];
#pragma unroll
        for (int mt = 0; mt < 4; ++mt) {
#pragma unroll
            for (int r = 0; r < 4; ++r) {
                int m = m0 + Wm * 64 + mt * 16 + 4 * lg + r;
                out[(size_t)m * 512 + n] = acc[mt][nt][r] + pb;
            }
        }
    }
}

// =================== FALLBACK (round-2 path, proven) ===================
__global__ void prep2_kernel(const float* __restrict__ qkv_w,
                             const float* __restrict__ proj_w,
                             const float* __restrict__ bias_table,
                             unsigned short* __restrict__ wqkv_f,
                             unsigned short* __restrict__ wproj_f,
                             float* __restrict__ bias_f) {
    int b = blockIdx.x, t = threadIdx.x;
    if (b < 384) {
        int gid = b * 256 + t;
        int l = gid & 63; int r = gid >> 6;
        int dh = r & 1; r >>= 1;
        int ks = r & 15; r >>= 4;
        int h = r & 15; int which = r >> 4;
        int d = dh * 16 + (l & 15);
        int row = h * 96 + d * 3 + which;
        int c0 = ks * 32 + (l >> 4) * 8;
        const float* src = qkv_w + row * 512 + c0;
        unsigned short o[8];
#pragma unroll
        for (int j = 0; j < 8; ++j) o[j] = f2bf(src[j]);
        *(uint4*)(wqkv_f + (size_t)gid * 8) = pack8(o);
    } else if (b < 512) {
        int gid = (b - 384) * 256 + t;
        const float* src = proj_w + (size_t)gid * 8;
        unsigned short o[8];
#pragma unroll
        for (int j = 0; j < 8; ++j) o[j] = f2bf(src[j]);
        *(uint4*)(wproj_f + (size_t)gid * 8) = pack8(o);
    } else {
        int gid = (b - 512) * 256 + t;
        int j = gid & 63; int i = (gid >> 6) & 63; int h = gid >> 12;
        float v = -1e30f;
        if (i < 49 && j < 49) {
            int ri = i / 7, ci = i % 7, rj = j / 7, cj = j % 7;
            int idx = (ri - rj + 6) * 13 + (ci - cj + 6);
            v = bias_table[idx * 16 + h];
        }
        bias_f[gid] = v;
    }
}

__global__ __launch_bounds__(256, 2)
void attn_qkv_kernel(const float* __restrict__ x,
                     const float* __restrict__ qkv_b,
                     const unsigned short* __restrict__ wqkv_f,
                     const float* __restrict__ bias_f,
                     unsigned short* __restrict__ attnout) {
    __shared__ __align__(16) char smem[81920];
    const int tid = threadIdx.x;
    const int l = tid & 63;
    const int W = tid >> 6;
    const int lr = l & 15;
    const int lg = l >> 4;
    const int win = blockIdx.x;

    bf16x8 xf[16];
    {
        int trow = 16 * W + lr; if (trow > 48) trow = 48;
        const float* xr = x + ((size_t)win * 49 + trow) * 512;
#pragma unroll
        for (int ks = 0; ks < 16; ++ks) {
            float4 a = *(const float4*)(xr + ks * 32 + lg * 8);
            float4 b = *(const float4*)(xr + ks * 32 + lg * 8 + 4);
            BU8 u;
            u.s[0] = f2bf(a.x); u.s[1] = f2bf(a.y); u.s[2] = f2bf(a.z); u.s[3] = f2bf(a.w);
            u.s[4] = f2bf(b.x); u.s[5] = f2bf(b.y); u.s[6] = f2bf(b.z); u.s[7] = f2bf(b.w);
            xf[ks] = u.v;
        }
    }

    const f32x4 zf = {0.f, 0.f, 0.f, 0.f};
    unsigned short* ao = attnout + (size_t)win * (49 * 512);

    for (int hg = 0; hg < 4; ++hg) {
        for (int h2 = 0; h2 < 4; ++h2) {
            int h = hg * 4 + h2;
            char* qk = smem + h2 * 8192;
            char* vt = smem + 32768 + h2 * 4096;
#pragma unroll 1
            for (int which = 0; which < 3; ++which) {
                f32x4 a0 = zf, a1 = zf;
                const unsigned short* bp =
                    wqkv_f + (size_t)(which * 16 + h) * 16384 + l * 8;
#pragma unroll
                for (int ks = 0; ks < 16; ++ks) {
                    bf16x8 b0 = *(const bf16x8*)(bp + ks * 1024);
                    bf16x8 b1 = *(const bf16x8*)(bp + ks * 1024 + 512);
                    a0 = __builtin_amdgcn_mfma_f32_16x16x32_bf16(xf[ks], b0, a0, 0, 0, 0);
                    a1 = __builtin_amdgcn_mfma_f32_16x16x32_bf16(xf[ks], b1, a1, 0, 0, 0);
                }
                float bias0 = qkv_b[h * 96 + lr * 3 + which];
                float bias1 = qkv_b[h * 96 + (16 + lr) * 3 + which];
                if (which == 2) {
                    int d0 = lr, d1 = 16 + lr;
#pragma unroll
                    for (int r = 0; r < 4; ++r) {
                        int t = 16 * W + 4 * lg + r;
                        *(unsigned short*)(vt + d0 * 128 + ((t * 2) ^ ((d0 & 7) << 4))) =
                            f2bf(a0[r] + bias0);
                        *(unsigned short*)(vt + d1 * 128 + ((t * 2) ^ ((d1 & 7) << 4))) =
                            f2bf(a1[r] + bias1);
                    }
                } else {
                    float sc = (which == 0) ? SCALE_Q : 1.0f;
                    int cb = which * 64;
#pragma unroll
                    for (int r = 0; r < 4; ++r) {
                        int t = 16 * W + 4 * lg + r;
                        int sw = (t & 7) << 4;
                        *(unsigned short*)(qk + t * 128 + ((cb + lr * 2) ^ sw)) =
                            f2bf((a0[r] + bias0) * sc);
                        *(unsigned short*)(qk + t * 128 + ((cb + 32 + lr * 2) ^ sw)) =
                            f2bf((a1[r] + bias1) * sc);
                    }
                }
            }
        }
        __syncthreads();
        {
            int h = hg * 4 + W;
            char* qk = smem + W * 8192;
            char* vt = smem + 32768 + W * 4096;
            char* P  = smem + 49152 + W * 8192;

            bf16x8 kf[4], qf[4];
#pragma unroll
            for (int i = 0; i < 4; ++i) {
                int row = i * 16 + lr;
                int sw = (row & 7) << 4;
                qf[i] = *(const bf16x8*)(qk + row * 128 + ((lg * 16) ^ sw));
                kf[i] = *(const bf16x8*)(qk + row * 128 + ((64 + lg * 16) ^ sw));
            }
            f32x4 s[4][4];
#pragma unroll
            for (int mt = 0; mt < 4; ++mt)
#pragma unroll
                for (int qt = 0; qt < 4; ++qt)
                    s[mt][qt] = __builtin_amdgcn_mfma_f32_16x16x32_bf16(
                        kf[mt], qf[qt], zf, 0, 0, 0);
#pragma unroll
            for (int qt = 0; qt < 4; ++qt) {
                int q = qt * 16 + lr;
                const float* bb = bias_f + ((size_t)h * 64 + q) * 64;
#pragma unroll
                for (int mt = 0; mt < 4; ++mt) {
                    float4 b4 = *(const float4*)(bb + mt * 16 + lg * 4);
                    s[mt][qt][0] += b4.x; s[mt][qt][1] += b4.y;
                    s[mt][qt][2] += b4.z; s[mt][qt][3] += b4.w;
                }
            }
#pragma unroll
            for (int qt = 0; qt < 4; ++qt) {
                float m = -1e30f;
#pragma unroll
                for (int mt = 0; mt < 4; ++mt)
#pragma unroll
                    for (int r = 0; r < 4; ++r) m = fmaxf(m, s[mt][qt][r]);
                m = fmaxf(m, __shfl_xor(m, 16));
                m = fmaxf(m, __shfl_xor(m, 32));
                float sum = 0.f;
#pragma unroll
                for (int mt = 0; mt < 4; ++mt)
#pragma unroll
                    for (int r = 0; r < 4; ++r) {
                        float p = __expf(s[mt][qt][r] - m);
                        s[mt][qt][r] = p; sum += p;
                    }
                sum += __shfl_xor(sum, 16);
                sum += __shfl_xor(sum, 32);
                float inv = 1.0f / sum;
                int qrow = qt * 16 + lr;
                int sw = (qrow & 7) << 4;
#pragma unroll
                for (int mt = 0; mt < 4; ++mt) {
                    uint2 uv;
                    uv.x = (unsigned)f2bf(s[mt][qt][0] * inv) |
                           ((unsigned)f2bf(s[mt][qt][1] * inv) << 16);
                    uv.y = (unsigned)f2bf(s[mt][qt][2] * inv) |
                           ((unsigned)f2bf(s[mt][qt][3] * inv) << 16);
                    *(uint2*)(P + qrow * 128 + ((mt * 32 + lg * 8) ^ sw)) = uv;
                }
            }
            bf16x8 vf[2][2];
#pragma unroll
            for (int ks = 0; ks < 2; ++ks)
#pragma unroll
                for (int nt = 0; nt < 2; ++nt) {
                    int d = nt * 16 + lr;
                    vf[ks][nt] = *(const bf16x8*)(vt + d * 128 +
                        ((ks * 64 + lg * 16) ^ ((d & 7) << 4)));
                }
            f32x4 o[4][2];
#pragma unroll
            for (int mt = 0; mt < 4; ++mt) {
                o[mt][0] = zf; o[mt][1] = zf;
                int q = mt * 16 + lr;
                int sw = (q & 7) << 4;
#pragma unroll
                for (int ks = 0; ks < 2; ++ks) {
                    bf16x8 pf = *(const bf16x8*)(P + q * 128 + ((ks * 64 + lg * 16) ^ sw));
                    o[mt][0] = __builtin_amdgcn_mfma_f32_16x16x32_bf16(pf, vf[ks][0], o[mt][0], 0, 0, 0);
                    o[mt][1] = __builtin_amdgcn_mfma_f32_16x16x32_bf16(pf, vf[ks][1], o[mt][1], 0, 0, 0);
                }
            }
#pragma unroll
            for (int mt = 0; mt < 4; ++mt)
#pragma unroll
                for (int nt = 0; nt < 2; ++nt)
#pragma unroll
                    for (int r = 0; r < 4; ++r) {
                        int q = mt * 16 + 4 * lg + r;
                        if (q < 49)
                            ao[q * 512 + h * 32 + nt * 16 + lr] = f2bf(o[mt][nt][r]);
                    }
        }
        __syncthreads();
    }
}

extern "C" void kernel_launch(void* const* d_in, const int* in_sizes, int n_in,
                              void* d_out, int out_size, void* d_ws, size_t ws_size,
                              hipStream_t stream) {
    const float* x          = (const float*)d_in[0];
    const float* qkv_w      = (const float*)d_in[1];
    const float* qkv_b      = (const float*)d_in[2];
    const float* proj_w     = (const float*)d_in[3];
    const float* proj_b     = (const float*)d_in[4];
    const float* bias_table = (const float*)d_in[5];

    unsigned short* wqkv_f  = (unsigned short*)d_ws;
    unsigned short* wproj_f = wqkv_f + 786432;                 // @1.5MB
    float*          bias_f  = (float*)(wproj_f + 262144);      // @2.0MB

    if (ws_size >= WS2) {
        float* qkvb_r = (float*)((char*)d_ws + 2359296);
        unsigned short* xs      = (unsigned short*)((char*)d_ws + OFF_XS);
        unsigned short* attnout = (unsigned short*)((char*)d_ws + OFF_ATTN);
        hipLaunchKernelGGL(prepN_kernel, dim3(4865), dim3(256), 0, stream,
                           x, qkv_w, qkv_b, proj_w, bias_table,
                           wqkv_f, wproj_f, bias_f, qkvb_r, xs);
        hipLaunchKernelGGL(qkvattn_kernel, dim3(8192), dim3(256), 0, stream,
                           xs, wqkv_f, qkvb_r, bias_f, attnout);
        hipLaunchKernelGGL(proj_kernel, dim3(3136), dim3(256), 0, stream,
                           attnout, wproj_f, proj_b, (float*)d_out);
    } else if (ws_size >= WS_R2) {
        unsigned short* attnout = (unsigned short*)((char*)d_ws + 2359296);
        hipLaunchKernelGGL(prep2_kernel, dim3(768), dim3(256), 0, stream,
                           qkv_w, proj_w, bias_table, wqkv_f, wproj_f, bias_f);
        hipLaunchKernelGGL(attn_qkv_kernel, dim3(2048), dim3(256), 0, stream,
                           x, qkv_b, wqkv_f, bias_f, attnout);
        hipLaunchKernelGGL(proj_kernel, dim3(3136), dim3(256), 0, stream,
                           attnout, wproj_f, proj_b, (float*)d_out);
    }
}

// Round 14
// 473.637 us; speedup vs baseline: 1.1391x; 1.1391x over previous
//
#include <hip/hip_runtime.h>

// WindowAttention for MI355X (gfx950) — round 14.
// R11 host (proven 300us qkvattn) + q/k row-stride padding 32->36 elements:
//  q/k fragment ds_read_b128 bank-start = (row*18+lg*4)%32 -> 16 slots
//  (4-way) instead of 8 slots (8-way). Same fix applies to the scatter
//  stores. LDS/window = q[64][36]+k[64][36]+vt[32][64] = 13312B; x4 = 53248B
//  -> still 3 blocks/CU. R13's A-direct (regressed) reverted; R12's null
//  levers stay out.
//  prepN / proj: unchanged (proven, xs swizzled again).
// Fallback: R2 path if ws too small.

typedef __bf16 bf16x8 __attribute__((ext_vector_type(8)));
typedef float f32x4 __attribute__((ext_vector_type(4)));

#define SCALE_Q 0.17677669529663687f

// ---- ws layout (bytes), new path ----
//  [0,        1572864)    wqkv_f  bf16 [1536][512], row c = head*96+which*32+d
//  [1572864,  2097152)    wproj_f bf16 [512][512] row-major
//  [2097152,  2359296)    bias_f  f32 [16][64][64], -1e30 pads
//  [2359296,  2365440)    qkvb_r  f32 [1536] reordered (head,which,d)
//  [2365440,  136583168)  xs      bf16 [131072][512] padded, pre-swizzled
//  [136583168,239343616)  attnout bf16 [100352][512] compact
#define OFF_XS     2365440ull
#define OFF_ATTN   136583168ull
#define WS2        507779072ull
#define WS_R2      105119744ull

// qkv LDS geometry (elements): q[64][36] @0, k[64][36] @2304, vt[32][64] @4608
#define QK_STRIDE 36
#define K_OFF     2304
#define VT_OFF    4608
#define WIN_ELEMS 6656       // 13312 bytes per window

// native RNE f32->bf16 (compiler emits v_cvt_pk_bf16_f32 for pairs)
__device__ __forceinline__ unsigned short bfc(float f) {
    union { __bf16 b; unsigned short u; } x; x.b = (__bf16)f; return x.u;
}

__device__ __forceinline__ uint4 cvt8(const float f[8]) {
    uint4 p;
    p.x = (unsigned)bfc(f[0]) | ((unsigned)bfc(f[1]) << 16);
    p.y = (unsigned)bfc(f[2]) | ((unsigned)bfc(f[3]) << 16);
    p.z = (unsigned)bfc(f[4]) | ((unsigned)bfc(f[5]) << 16);
    p.w = (unsigned)bfc(f[6]) | ((unsigned)bfc(f[7]) << 16);
    return p;
}

__device__ __forceinline__ unsigned short f2bf(float f) {
    unsigned int u = __float_as_uint(f);
    u += 0x7FFFu + ((u >> 16) & 1u);
    return (unsigned short)(u >> 16);
}

__device__ __forceinline__ uint4 pack8(const unsigned short o[8]) {
    uint4 p;
    p.x = (unsigned)o[0] | ((unsigned)o[1] << 16);
    p.y = (unsigned)o[2] | ((unsigned)o[3] << 16);
    p.z = (unsigned)o[4] | ((unsigned)o[5] << 16);
    p.w = (unsigned)o[6] | ((unsigned)o[7] << 16);
    return p;
}

union BU8 { bf16x8 v; unsigned short s[8]; };

#define GLOAD16(g, l) __builtin_amdgcn_global_load_lds( \
    (__attribute__((address_space(1))) void*)(void*)(g), \
    (__attribute__((address_space(3))) void*)(l), 16, 0, 0)

// ================= prepN =================
__global__ void prepN_kernel(const float* __restrict__ x,
                             const float* __restrict__ qkv_w,
                             const float* __restrict__ qkv_b,
                             const float* __restrict__ proj_w,
                             const float* __restrict__ bias_table,
                             unsigned short* __restrict__ wqkv_f,
                             unsigned short* __restrict__ wproj_f,
                             float* __restrict__ bias_f,
                             float* __restrict__ qkvb_r,
                             unsigned short* __restrict__ xs) {
    int b = blockIdx.x, t = threadIdx.x;
    if (b < 384) {
        // wqkv_f[c][k], c = head*96 + which*32 + d  <-  qkv_w[head*96+d*3+which]
        int gid = b * 256 + t;              // 98304 = 1536*64
        int c = gid >> 6, k8 = (gid & 63) * 8;
        int head = c / 96, rem = c - head * 96;
        int which = rem >> 5, d = rem & 31;
        const float* src = qkv_w + (size_t)(head * 96 + d * 3 + which) * 512 + k8;
        float f[8];
#pragma unroll
        for (int j = 0; j < 8; ++j) f[j] = src[j];
        *(uint4*)(wqkv_f + (size_t)c * 512 + k8) = cvt8(f);
    } else if (b < 512) {
        int gid = (b - 384) * 256 + t;      // 32768 * 8 = 512*512
        const float* src = proj_w + (size_t)gid * 8;
        float f[8];
#pragma unroll
        for (int j = 0; j < 8; ++j) f[j] = src[j];
        *(uint4*)(wproj_f + (size_t)gid * 8) = cvt8(f);
    } else if (b < 768) {
        int gid = (b - 512) * 256 + t;      // 65536
        int j = gid & 63; int i = (gid >> 6) & 63; int h = gid >> 12;
        float v = -1e30f;
        if (i < 49 && j < 49) {
            int ri = i / 7, ci = i % 7, rj = j / 7, cj = j % 7;
            int idx = (ri - rj + 6) * 13 + (ci - cj + 6);
            v = bias_table[idx * 16 + h];
        }
        bias_f[gid] = v;
    } else if (b == 768) {
        for (int c = t; c < 1536; c += 256) {
            int head = c / 96, rem = c - head * 96;
            int which = rem >> 5, d = rem & 31;
            qkvb_r[c] = qkv_b[head * 96 + d * 3 + which];
        }
    } else {
        // x -> bf16 PADDED [131072][512], pre-swizzled by dest row&7.
        int gid = (b - 769) * 256 + t;      // < 1048576 = 131072*8
        int row = gid >> 3, kt = gid & 7;
        int win = row >> 6, tok = row & 63; if (tok > 48) tok = 48;
        int sw = row & 7;
        const float* src = x + ((size_t)win * 49 + tok) * 512 + kt * 64;
        unsigned short* dst = xs + (size_t)row * 512 + kt * 64;
#pragma unroll
        for (int c = 0; c < 8; ++c) {
            int cs = (c ^ sw) * 8;
            float f[8];
            *(float4*)&f[0] = *(const float4*)(src + cs);
            *(float4*)&f[4] = *(const float4*)(src + cs + 4);
            *(uint4*)(dst + c * 8) = cvt8(f);
        }
    }
}

// ================= K1: fused QKV GEMM + attention =================
// block = (mb: 4 windows, head), 256 threads / 4 waves, wave = 64 M-rows.
// LDS (53248 B total, time-overlaid):
//  GEMM phase:  A stage [0,32768), B stage [32768,45056)
//  post-GEMM:   qkv [0,53248) = 4 win x {q[64][36],k[64][36],vt[32][64]} (13312B ea)
//               P (8KB/wave) overlays wave's OWN window's dead q+k (9216B)
__global__ __launch_bounds__(256, 3)
void qkvattn_kernel(const unsigned short* __restrict__ xs,
                    const unsigned short* __restrict__ wqkv_f,
                    const float* __restrict__ qkvb_r,
                    const float* __restrict__ bias_f,
                    unsigned short* __restrict__ attnout) {
    __shared__ __align__(16) char smem[53248];
    char* As = smem;
    char* Bs = smem + 32768;

    // XCD swizzle: 8192 blocks = 8 * 1024; head-inner within an XCD.
    int i = blockIdx.x;
    int virt = (i & 7) * 1024 + (i >> 3);
    int mb = virt >> 4, head = virt & 15;   // mb: 0..511 (4 windows each)
    int m0 = mb * 256;

    const int tid = threadIdx.x;
    const int l = tid & 63;
    const int W = tid >> 6;
    const int lr = l & 15;
    const int lg = l >> 4;

    f32x4 acc[4][6];
    const f32x4 zf = {0.f, 0.f, 0.f, 0.f};
#pragma unroll
    for (int mt = 0; mt < 4; ++mt)
#pragma unroll
        for (int nt = 0; nt < 6; ++nt) acc[mt][nt] = zf;

    int rsub = l >> 3, csub = l & 7;
    int cswz = (csub ^ rsub) * 16;         // B runtime inverse-swizzle
    int clin = csub * 16;                  // A linear (xs pre-swizzled)

    const char* bbase = (const char*)wqkv_f + (size_t)head * 96 * 1024;
    const char* abase = (const char*)xs + ((size_t)m0 * 512) * 2;

#pragma unroll 1
    for (int kt = 0; kt < 8; ++kt) {
        int ko = kt * 128;                 // byte offset of k-tile (64 bf16)
        // A: 256 rows x 128B; 8 loads/thread
#pragma unroll
        for (int ii = 0; ii < 8; ++ii) {
            int r = ii * 32 + W * 8 + rsub;
            GLOAD16(abase + (size_t)r * 1024 + ko + clin, As + ii * 4096 + W * 1024);
        }
        // B: 96 rows x 128B; 3 loads/thread
#pragma unroll
        for (int jj = 0; jj < 3; ++jj) {
            int r = jj * 32 + W * 8 + rsub;
            GLOAD16(bbase + (size_t)r * 1024 + ko + cswz, Bs + jj * 4096 + W * 1024);
        }
        __syncthreads();
#pragma unroll
        for (int ks = 0; ks < 2; ++ks) {
            bf16x8 af[4], bf[6];
#pragma unroll
            for (int mt = 0; mt < 4; ++mt) {
                int row = W * 64 + mt * 16 + lr;
                af[mt] = *(const bf16x8*)(As + row * 128 +
                    ((ks * 64 + lg * 16) ^ ((row & 7) << 4)));
            }
#pragma unroll
            for (int nt = 0; nt < 6; ++nt) {
                int row = nt * 16 + lr;
                bf[nt] = *(const bf16x8*)(Bs + row * 128 +
                    ((ks * 64 + lg * 16) ^ ((row & 7) << 4)));
            }
#pragma unroll
            for (int mt = 0; mt < 4; ++mt)
#pragma unroll
                for (int nt = 0; nt < 6; ++nt)
                    acc[mt][nt] = __builtin_amdgcn_mfma_f32_16x16x32_bf16(
                        af[mt], bf[nt], acc[mt][nt], 0, 0, 0);
        }
        __syncthreads();
    }

    // ---- scatter acc -> qkv LDS (overlays dead A/B stage) ----
    // wave W owns window W: all 64 toks x 96 cols -> wave-local from here on.
    unsigned short* wbuf = (unsigned short*)smem + W * WIN_ELEMS;
    {
        int tokb = 4 * lg;
#pragma unroll
        for (int nt = 0; nt < 6; ++nt) {
            const int which = nt >> 1;
            const int d = (nt & 1) * 16 + lr;
            float bias = qkvb_r[head * 96 + which * 32 + d];
            float sc = (which == 0) ? SCALE_Q : 1.0f;
#pragma unroll
            for (int mt = 0; mt < 4; ++mt) {
                int tok0 = tokb + mt * 16;
                if (which == 2) {
                    // vt[d][tok], tok-chunk XOR swizzle; 4 toks in one chunk
                    int idx = VT_OFF + d * 64 + (((tok0 >> 3) ^ (d & 7)) << 3) + (tok0 & 7);
                    ushort4 u;
                    u.x = bfc(acc[mt][nt][0] + bias);
                    u.y = bfc(acc[mt][nt][1] + bias);
                    u.z = bfc(acc[mt][nt][2] + bias);
                    u.w = bfc(acc[mt][nt][3] + bias);
                    *(ushort4*)(wbuf + idx) = u;
                } else {
#pragma unroll
                    for (int r = 0; r < 4; ++r)
                        wbuf[which * K_OFF + (tok0 + r) * QK_STRIDE + d] =
                            bfc((acc[mt][nt][r] + bias) * sc);
                }
            }
        }
    }
    // no barrier: attention below is entirely wave-local (wave = its window)

    // ---- attention: wave W = window W (64 q rows), barrier-free ----
    {
        const unsigned short* qa = wbuf;
        char* P = smem + W * (WIN_ELEMS * 2);   // 8KB, overlays own dead q+k
        int win_g = mb * 4 + W;
        unsigned short* ao = attnout + (size_t)win_g * (49 * 512);

        bf16x8 qf[4], kf[4], vf[2][2];
#pragma unroll
        for (int i2 = 0; i2 < 4; ++i2) {
            qf[i2] = *(const bf16x8*)(qa + (i2 * 16 + lr) * QK_STRIDE + lg * 8);
            kf[i2] = *(const bf16x8*)(qa + K_OFF + (i2 * 16 + lr) * QK_STRIDE + lg * 8);
        }
#pragma unroll
        for (int ks = 0; ks < 2; ++ks)
#pragma unroll
            for (int nt = 0; nt < 2; ++nt) {
                int d = nt * 16 + lr;
                vf[ks][nt] = *(const bf16x8*)(qa + VT_OFF + d * 64 +
                    (((ks * 4 + lg) ^ (d & 7)) << 3));
            }

        // S^T[kv][q]
        f32x4 s[4][4];
#pragma unroll
        for (int mt = 0; mt < 4; ++mt)
#pragma unroll
            for (int qt = 0; qt < 4; ++qt)
                s[mt][qt] = __builtin_amdgcn_mfma_f32_16x16x32_bf16(
                    kf[mt], qf[qt], zf, 0, 0, 0);
        // bias (kv pads = -1e30)
#pragma unroll
        for (int qt = 0; qt < 4; ++qt) {
            int q = qt * 16 + lr;
            const float* bb = bias_f + ((size_t)head * 64 + q) * 64;
#pragma unroll
            for (int mt = 0; mt < 4; ++mt) {
                float4 b4 = *(const float4*)(bb + mt * 16 + lg * 4);
                s[mt][qt][0] += b4.x; s[mt][qt][1] += b4.y;
                s[mt][qt][2] += b4.z; s[mt][qt][3] += b4.w;
            }
        }
        // softmax per q column; P -> LDS bf16 (overwrites own q/k — reads done)
#pragma unroll
        for (int qt = 0; qt < 4; ++qt) {
            float m = -1e30f;
#pragma unroll
            for (int mt = 0; mt < 4; ++mt)
#pragma unroll
                for (int r = 0; r < 4; ++r) m = fmaxf(m, s[mt][qt][r]);
            m = fmaxf(m, __shfl_xor(m, 16));
            m = fmaxf(m, __shfl_xor(m, 32));
            float sum = 0.f;
#pragma unroll
            for (int mt = 0; mt < 4; ++mt)
#pragma unroll
                for (int r = 0; r < 4; ++r) {
                    float p = __expf(s[mt][qt][r] - m);
                    s[mt][qt][r] = p; sum += p;
                }
            sum += __shfl_xor(sum, 16);
            sum += __shfl_xor(sum, 32);
            float inv = 1.0f / sum;
            int ql = qt * 16 + lr;          // 0..63
            int sw = (ql & 7) << 4;
#pragma unroll
            for (int mt = 0; mt < 4; ++mt) {
                uint2 uv;
                uv.x = (unsigned)bfc(s[mt][qt][0] * inv) |
                       ((unsigned)bfc(s[mt][qt][1] * inv) << 16);
                uv.y = (unsigned)bfc(s[mt][qt][2] * inv) |
                       ((unsigned)bfc(s[mt][qt][3] * inv) << 16);
                *(uint2*)(P + ql * 128 + ((mt * 32 + lg * 8) ^ sw)) = uv;
            }
        }
        // PV
        f32x4 o[4][2];
#pragma unroll
        for (int mt = 0; mt < 4; ++mt) {
            o[mt][0] = zf; o[mt][1] = zf;
            int ql = mt * 16 + lr;
            int sw = (ql & 7) << 4;
#pragma unroll
            for (int ks = 0; ks < 2; ++ks) {
                bf16x8 pf = *(const bf16x8*)(P + ql * 128 + ((ks * 64 + lg * 16) ^ sw));
                o[mt][0] = __builtin_amdgcn_mfma_f32_16x16x32_bf16(pf, vf[ks][0], o[mt][0], 0, 0, 0);
                o[mt][1] = __builtin_amdgcn_mfma_f32_16x16x32_bf16(pf, vf[ks][1], o[mt][1], 0, 0, 0);
            }
        }
#pragma unroll
        for (int mt = 0; mt < 4; ++mt)
#pragma unroll
            for (int nt = 0; nt < 2; ++nt)
#pragma unroll
                for (int r = 0; r < 4; ++r) {
                    int q = mt * 16 + 4 * lg + r;
                    if (q < 49)
                        ao[q * 512 + head * 32 + nt * 16 + lr] = bfc(o[mt][nt][r]);
                }
    }
}

// ================= K3: proj GEMM (unchanged, proven) =================
__global__ __launch_bounds__(256, 2)
void proj_kernel(const unsigned short* __restrict__ attnout,
                 const unsigned short* __restrict__ wproj_f,
                 const float* __restrict__ proj_b,
                 float* __restrict__ out) {
    __shared__ __align__(16) char smem[32768];
    char* As = smem;
    char* Bs = smem + 16384;

    int bid = blockIdx.x;
    int c = bid >> 2;
    int cs = (c & 7) * 98 + (c >> 3);
    int m0 = cs * 128;
    int n0 = (bid & 3) * 128;

    const int tid = threadIdx.x;
    const int l = tid & 63;
    const int W = tid >> 6;
    const int lr = l & 15;
    const int lg = l >> 4;
    const int Wm = W >> 1, Wn = W & 1;

    f32x4 acc[4][4];
    const f32x4 zf = {0.f, 0.f, 0.f, 0.f};
#pragma unroll
    for (int mt = 0; mt < 4; ++mt)
#pragma unroll
        for (int nt = 0; nt < 4; ++nt) acc[mt][nt] = zf;

    int rsub = l >> 3;
    int csub = l & 7;
    int cswz = (csub ^ rsub) * 16;

#pragma unroll 1
    for (int kt = 0; kt < 8; ++kt) {
#pragma unroll
        for (int i = 0; i < 4; ++i) {
            int r = i * 32 + W * 8 + rsub;
            const char* srcA = (const char*)attnout +
                ((size_t)(m0 + r) * 512 + kt * 64) * 2 + cswz;
            GLOAD16(srcA, As + i * 4096 + W * 1024);
            const char* srcB = (const char*)wproj_f +
                ((size_t)(n0 + r) * 512 + kt * 64) * 2 + cswz;
            GLOAD16(srcB, Bs + i * 4096 + W * 1024);
        }
        __syncthreads();
#pragma unroll
        for (int ks = 0; ks < 2; ++ks) {
            bf16x8 af[4], bf[4];
#pragma unroll
            for (int mt = 0; mt < 4; ++mt) {
                int row = Wm * 64 + mt * 16 + lr;
                af[mt] = *(const bf16x8*)(As + row * 128 +
                    ((ks * 64 + lg * 16) ^ ((row & 7) << 4)));
            }
#pragma unroll
            for (int nt = 0; nt < 4; ++nt) {
                int row = Wn * 64 + nt * 16 + lr;
                bf[nt] = *(const bf16x8*)(Bs + row * 128 +
                    ((ks * 64 + lg * 16) ^ ((row & 7) << 4)));
            }
#pragma unroll
            for (int mt = 0; mt < 4; ++mt)
#pragma unroll
                for (int nt = 0; nt < 4; ++nt)
                    acc[mt][nt] = __builtin_amdgcn_mfma_f32_16x16x32_bf16(
                        af[mt], bf[nt], acc[mt][nt], 0, 0, 0);
        }
        __syncthreads();
    }
#pragma unroll
    for (int nt = 0; nt < 4; ++nt) {
        int n = n0 + Wn * 64 + nt * 16 + lr;
        float pb = proj_b[n];
#pragma unroll
        for (int mt = 0; mt < 4; ++mt) {
#pragma unroll
            for (int r = 0; r < 4; ++r) {
                int m = m0 + Wm * 64 + mt * 16 + 4 * lg + r;
                out[(size_t)m * 512 + n] = acc[mt][nt][r] + pb;
            }
        }
    }
}

// =================== FALLBACK (round-2 path, proven) ===================
__global__ void prep2_kernel(const float* __restrict__ qkv_w,
                             const float* __restrict__ proj_w,
                             const float* __restrict__ bias_table,
                             unsigned short* __restrict__ wqkv_f,
                             unsigned short* __restrict__ wproj_f,
                             float* __restrict__ bias_f) {
    int b = blockIdx.x, t = threadIdx.x;
    if (b < 384) {
        int gid = b * 256 + t;
        int l = gid & 63; int r = gid >> 6;
        int dh = r & 1; r >>= 1;
        int ks = r & 15; r >>= 4;
        int h = r & 15; int which = r >> 4;
        int d = dh * 16 + (l & 15);
        int row = h * 96 + d * 3 + which;
        int c0 = ks * 32 + (l >> 4) * 8;
        const float* src = qkv_w + row * 512 + c0;
        unsigned short o[8];
#pragma unroll
        for (int j = 0; j < 8; ++j) o[j] = f2bf(src[j]);
        *(uint4*)(wqkv_f + (size_t)gid * 8) = pack8(o);
    } else if (b < 512) {
        int gid = (b - 384) * 256 + t;
        const float* src = proj_w + (size_t)gid * 8;
        unsigned short o[8];
#pragma unroll
        for (int j = 0; j < 8; ++j) o[j] = f2bf(src[j]);
        *(uint4*)(wproj_f + (size_t)gid * 8) = pack8(o);
    } else {
        int gid = (b - 512) * 256 + t;
        int j = gid & 63; int i = (gid >> 6) & 63; int h = gid >> 12;
        float v = -1e30f;
        if (i < 49 && j < 49) {
            int ri = i / 7, ci = i % 7, rj = j / 7, cj = j % 7;
            int idx = (ri - rj + 6) * 13 + (ci - cj + 6);
            v = bias_table[idx * 16 + h];
        }
        bias_f[gid] = v;
    }
}

__global__ __launch_bounds__(256, 2)
void attn_qkv_kernel(const float* __restrict__ x,
                     const float* __restrict__ qkv_b,
                     const unsigned short* __restrict__ wqkv_f,
                     const float* __restrict__ bias_f,
                     unsigned short* __restrict__ attnout) {
    __shared__ __align__(16) char smem[81920];
    const int tid = threadIdx.x;
    const int l = tid & 63;
    const int W = tid >> 6;
    const int lr = l & 15;
    const int lg = l >> 4;
    const int win = blockIdx.x;

    bf16x8 xf[16];
    {
        int trow = 16 * W + lr; if (trow > 48) trow = 48;
        const float* xr = x + ((size_t)win * 49 + trow) * 512;
#pragma unroll
        for (int ks = 0; ks < 16; ++ks) {
            float4 a = *(const float4*)(xr + ks * 32 + lg * 8);
            float4 b = *(const float4*)(xr + ks * 32 + lg * 8 + 4);
            BU8 u;
            u.s[0] = f2bf(a.x); u.s[1] = f2bf(a.y); u.s[2] = f2bf(a.z); u.s[3] = f2bf(a.w);
            u.s[4] = f2bf(b.x); u.s[5] = f2bf(b.y); u.s[6] = f2bf(b.z); u.s[7] = f2bf(b.w);
            xf[ks] = u.v;
        }
    }

    const f32x4 zf = {0.f, 0.f, 0.f, 0.f};
    unsigned short* ao = attnout + (size_t)win * (49 * 512);

    for (int hg = 0; hg < 4; ++hg) {
        for (int h2 = 0; h2 < 4; ++h2) {
            int h = hg * 4 + h2;
            char* qk = smem + h2 * 8192;
            char* vt = smem + 32768 + h2 * 4096;
#pragma unroll 1
            for (int which = 0; which < 3; ++which) {
                f32x4 a0 = zf, a1 = zf;
                const unsigned short* bp =
                    wqkv_f + (size_t)(which * 16 + h) * 16384 + l * 8;
#pragma unroll
                for (int ks = 0; ks < 16; ++ks) {
                    bf16x8 b0 = *(const bf16x8*)(bp + ks * 1024);
                    bf16x8 b1 = *(const bf16x8*)(bp + ks * 1024 + 512);
                    a0 = __builtin_amdgcn_mfma_f32_16x16x32_bf16(xf[ks], b0, a0, 0, 0, 0);
                    a1 = __builtin_amdgcn_mfma_f32_16x16x32_bf16(xf[ks], b1, a1, 0, 0, 0);
                }
                float bias0 = qkv_b[h * 96 + lr * 3 + which];
                float bias1 = qkv_b[h * 96 + (16 + lr) * 3 + which];
                if (which == 2) {
                    int d0 = lr, d1 = 16 + lr;
#pragma unroll
                    for (int r = 0; r < 4; ++r) {
                        int t = 16 * W + 4 * lg + r;
                        *(unsigned short*)(vt + d0 * 128 + ((t * 2) ^ ((d0 & 7) << 4))) =
                            f2bf(a0[r] + bias0);
                        *(unsigned short*)(vt + d1 * 128 + ((t * 2) ^ ((d1 & 7) << 4))) =
                            f2bf(a1[r] + bias1);
                    }
                } else {
                    float sc = (which == 0) ? SCALE_Q : 1.0f;
                    int cb = which * 64;
#pragma unroll
                    for (int r = 0; r < 4; ++r) {
                        int t = 16 * W + 4 * lg + r;
                        int sw = (t & 7) << 4;
                        *(unsigned short*)(qk + t * 128 + ((cb + lr * 2) ^ sw)) =
                            f2bf((a0[r] + bias0) * sc);
                        *(unsigned short*)(qk + t * 128 + ((cb + 32 + lr * 2) ^ sw)) =
                            f2bf((a1[r] + bias1) * sc);
                    }
                }
            }
        }
        __syncthreads();
        {
            int h = hg * 4 + W;
            char* qk = smem + W * 8192;
            char* vt = smem + 32768 + W * 4096;
            char* P  = smem + 49152 + W * 8192;

            bf16x8 kf[4], qf[4];
#pragma unroll
            for (int i = 0; i < 4; ++i) {
                int row = i * 16 + lr;
                int sw = (row & 7) << 4;
                qf[i] = *(const bf16x8*)(qk + row * 128 + ((lg * 16) ^ sw));
                kf[i] = *(const bf16x8*)(qk + row * 128 + ((64 + lg * 16) ^ sw));
            }
            f32x4 s[4][4];
#pragma unroll
            for (int mt = 0; mt < 4; ++mt)
#pragma unroll
                for (int qt = 0; qt < 4; ++qt)
                    s[mt][qt] = __builtin_amdgcn_mfma_f32_16x16x32_bf16(
                        kf[mt], qf[qt], zf, 0, 0, 0);
#pragma unroll
            for (int qt = 0; qt < 4; ++qt) {
                int q = qt * 16 + lr;
                const float* bb = bias_f + ((size_t)h * 64 + q) * 64;
#pragma unroll
                for (int mt = 0; mt < 4; ++mt) {
                    float4 b4 = *(const float4*)(bb + mt * 16 + lg * 4);
                    s[mt][qt][0] += b4.x; s[mt][qt][1] += b4.y;
                    s[mt][qt][2] += b4.z; s[mt][qt][3] += b4.w;
                }
            }
#pragma unroll
            for (int qt = 0; qt < 4; ++qt) {
                float m = -1e30f;
#pragma unroll
                for (int mt = 0; mt < 4; ++mt)
#pragma unroll
                    for (int r = 0; r < 4; ++r) m = fmaxf(m, s[mt][qt][r]);
                m = fmaxf(m, __shfl_xor(m, 16));
                m = fmaxf(m, __shfl_xor(m, 32));
                float sum = 0.f;
#pragma unroll
                for (int mt = 0; mt < 4; ++mt)
#pragma unroll
                    for (int r = 0; r < 4; ++r) {
                        float p = __expf(s[mt][qt][r] - m);
                        s[mt][qt][r] = p; sum += p;
                    }
                sum += __shfl_xor(sum, 16);
                sum += __shfl_xor(sum, 32);
                float inv = 1.0f / sum;
                int qrow = qt * 16 + lr;
                int sw = (qrow & 7) << 4;
#pragma unroll
                for (int mt = 0; mt < 4; ++mt) {
                    uint2 uv;
                    uv.x = (unsigned)f2bf(s[mt][qt][0] * inv) |
                           ((unsigned)f2bf(s[mt][qt][1] * inv) << 16);
                    uv.y = (unsigned)f2bf(s[mt][qt][2] * inv) |
                           ((unsigned)f2bf(s[mt][qt][3] * inv) << 16);
                    *(uint2*)(P + qrow * 128 + ((mt * 32 + lg * 8) ^ sw)) = uv;
                }
            }
            bf16x8 vf[2][2];
#pragma unroll
            for (int ks = 0; ks < 2; ++ks)
#pragma unroll
                for (int nt = 0; nt < 2; ++nt) {
                    int d = nt * 16 + lr;
                    vf[ks][nt] = *(const bf16x8*)(vt + d * 128 +
                        ((ks * 64 + lg * 16) ^ ((d & 7) << 4)));
                }
            f32x4 o[4][2];
#pragma unroll
            for (int mt = 0; mt < 4; ++mt) {
                o[mt][0] = zf; o[mt][1] = zf;
                int q = mt * 16 + lr;
                int sw = (q & 7) << 4;
#pragma unroll
                for (int ks = 0; ks < 2; ++ks) {
                    bf16x8 pf = *(const bf16x8*)(P + q * 128 + ((ks * 64 + lg * 16) ^ sw));
                    o[mt][0] = __builtin_amdgcn_mfma_f32_16x16x32_bf16(pf, vf[ks][0], o[mt][0], 0, 0, 0);
                    o[mt][1] = __builtin_amdgcn_mfma_f32_16x16x32_bf16(pf, vf[ks][1], o[mt][1], 0, 0, 0);
                }
            }
#pragma unroll
            for (int mt = 0; mt < 4; ++mt)
#pragma unroll
                for (int nt = 0; nt < 2; ++nt)
#pragma unroll
                    for (int r = 0; r < 4; ++r) {
                        int q = mt * 16 + 4 * lg + r;
                        if (q < 49)
                            ao[q * 512 + h * 32 + nt * 16 + lr] = f2bf(o[mt][nt][r]);
                    }
        }
        __syncthreads();
    }
}

extern "C" void kernel_launch(void* const* d_in, const int* in_sizes, int n_in,
                              void* d_out, int out_size, void* d_ws, size_t ws_size,
                              hipStream_t stream) {
    const float* x          = (const float*)d_in[0];
    const float* qkv_w      = (const float*)d_in[1];
    const float* qkv_b      = (const float*)d_in[2];
    const float* proj_w     = (const float*)d_in[3];
    const float* proj_b     = (const float*)d_in[4];
    const float* bias_table = (const float*)d_in[5];

    unsigned short* wqkv_f  = (unsigned short*)d_ws;
    unsigned short* wproj_f = wqkv_f + 786432;                 // @1.5MB
    float*          bias_f  = (float*)(wproj_f + 262144);      // @2.0MB

    if (ws_size >= WS2) {
        float* qkvb_r = (float*)((char*)d_ws + 2359296);
        unsigned short* xs      = (unsigned short*)((char*)d_ws + OFF_XS);
        unsigned short* attnout = (unsigned short*)((char*)d_ws + OFF_ATTN);
        hipLaunchKernelGGL(prepN_kernel, dim3(4865), dim3(256), 0, stream,
                           x, qkv_w, qkv_b, proj_w, bias_table,
                           wqkv_f, wproj_f, bias_f, qkvb_r, xs);
        hipLaunchKernelGGL(qkvattn_kernel, dim3(8192), dim3(256), 0, stream,
                           xs, wqkv_f, qkvb_r, bias_f, attnout);
        hipLaunchKernelGGL(proj_kernel, dim3(3136), dim3(256), 0, stream,
                           attnout, wproj_f, proj_b, (float*)d_out);
    } else if (ws_size >= WS_R2) {
        unsigned short* attnout = (unsigned short*)((char*)d_ws + 2359296);
        hipLaunchKernelGGL(prep2_kernel, dim3(768), dim3(256), 0, stream,
                           qkv_w, proj_w, bias_table, wqkv_f, wproj_f, bias_f);
        hipLaunchKernelGGL(attn_qkv_kernel, dim3(2048), dim3(256), 0, stream,
                           x, qkv_b, wqkv_f, bias_f, attnout);
        hipLaunchKernelGGL(proj_kernel, dim3(3136), dim3(256), 0, stream,
                           attnout, wproj_f, proj_b, (float*)d_out);
    }
}

// Round 15
// 466.682 us; speedup vs baseline: 1.1561x; 1.0149x over previous
//
#include <hip/hip_runtime.h>

// WindowAttention for MI355X (gfx950) — round 15.
// R14 host + (2 win x 2 head) block geometry: A-tile 128 rows (4 loads/thr,
// was 8), B-tile 192 rows (6 loads/thr, was 3). Per-barrier-drain outstanding
// loads 11->10 and the long-latency A population halves; A L2/L3 traffic
// 2GB->1GB. Wave W = (win=W&1, head=hp*2+(W>>1)); per-wave scatter/attention
// unchanged (slot W). LDS 53248, barriers, VGPR all unchanged.
// Fallback: R2 path if ws too small.

typedef __bf16 bf16x8 __attribute__((ext_vector_type(8)));
typedef float f32x4 __attribute__((ext_vector_type(4)));

#define SCALE_Q 0.17677669529663687f

// ---- ws layout (bytes), new path ----
//  [0,        1572864)    wqkv_f  bf16 [1536][512], row c = head*96+which*32+d
//  [1572864,  2097152)    wproj_f bf16 [512][512] row-major
//  [2097152,  2359296)    bias_f  f32 [16][64][64], -1e30 pads
//  [2359296,  2365440)    qkvb_r  f32 [1536] reordered (head,which,d)
//  [2365440,  136583168)  xs      bf16 [131072][512] padded, pre-swizzled
//  [136583168,239343616)  attnout bf16 [100352][512] compact
#define OFF_XS     2365440ull
#define OFF_ATTN   136583168ull
#define WS2        507779072ull
#define WS_R2      105119744ull

// qkv LDS geometry (elements): q[64][36] @0, k[64][36] @2304, vt[32][64] @4608
#define QK_STRIDE 36
#define K_OFF     2304
#define VT_OFF    4608
#define WIN_ELEMS 6656       // 13312 bytes per (win,head) slot

// native RNE f32->bf16 (compiler emits v_cvt_pk_bf16_f32 for pairs)
__device__ __forceinline__ unsigned short bfc(float f) {
    union { __bf16 b; unsigned short u; } x; x.b = (__bf16)f; return x.u;
}

__device__ __forceinline__ uint4 cvt8(const float f[8]) {
    uint4 p;
    p.x = (unsigned)bfc(f[0]) | ((unsigned)bfc(f[1]) << 16);
    p.y = (unsigned)bfc(f[2]) | ((unsigned)bfc(f[3]) << 16);
    p.z = (unsigned)bfc(f[4]) | ((unsigned)bfc(f[5]) << 16);
    p.w = (unsigned)bfc(f[6]) | ((unsigned)bfc(f[7]) << 16);
    return p;
}

__device__ __forceinline__ unsigned short f2bf(float f) {
    unsigned int u = __float_as_uint(f);
    u += 0x7FFFu + ((u >> 16) & 1u);
    return (unsigned short)(u >> 16);
}

__device__ __forceinline__ uint4 pack8(const unsigned short o[8]) {
    uint4 p;
    p.x = (unsigned)o[0] | ((unsigned)o[1] << 16);
    p.y = (unsigned)o[2] | ((unsigned)o[3] << 16);
    p.z = (unsigned)o[4] | ((unsigned)o[5] << 16);
    p.w = (unsigned)o[6] | ((unsigned)o[7] << 16);
    return p;
}

union BU8 { bf16x8 v; unsigned short s[8]; };

#define GLOAD16(g, l) __builtin_amdgcn_global_load_lds( \
    (__attribute__((address_space(1))) void*)(void*)(g), \
    (__attribute__((address_space(3))) void*)(l), 16, 0, 0)

// ================= prepN =================
__global__ void prepN_kernel(const float* __restrict__ x,
                             const float* __restrict__ qkv_w,
                             const float* __restrict__ qkv_b,
                             const float* __restrict__ proj_w,
                             const float* __restrict__ bias_table,
                             unsigned short* __restrict__ wqkv_f,
                             unsigned short* __restrict__ wproj_f,
                             float* __restrict__ bias_f,
                             float* __restrict__ qkvb_r,
                             unsigned short* __restrict__ xs) {
    int b = blockIdx.x, t = threadIdx.x;
    if (b < 384) {
        // wqkv_f[c][k], c = head*96 + which*32 + d  <-  qkv_w[head*96+d*3+which]
        int gid = b * 256 + t;              // 98304 = 1536*64
        int c = gid >> 6, k8 = (gid & 63) * 8;
        int head = c / 96, rem = c - head * 96;
        int which = rem >> 5, d = rem & 31;
        const float* src = qkv_w + (size_t)(head * 96 + d * 3 + which) * 512 + k8;
        float f[8];
#pragma unroll
        for (int j = 0; j < 8; ++j) f[j] = src[j];
        *(uint4*)(wqkv_f + (size_t)c * 512 + k8) = cvt8(f);
    } else if (b < 512) {
        int gid = (b - 384) * 256 + t;      // 32768 * 8 = 512*512
        const float* src = proj_w + (size_t)gid * 8;
        float f[8];
#pragma unroll
        for (int j = 0; j < 8; ++j) f[j] = src[j];
        *(uint4*)(wproj_f + (size_t)gid * 8) = cvt8(f);
    } else if (b < 768) {
        int gid = (b - 512) * 256 + t;      // 65536
        int j = gid & 63; int i = (gid >> 6) & 63; int h = gid >> 12;
        float v = -1e30f;
        if (i < 49 && j < 49) {
            int ri = i / 7, ci = i % 7, rj = j / 7, cj = j % 7;
            int idx = (ri - rj + 6) * 13 + (ci - cj + 6);
            v = bias_table[idx * 16 + h];
        }
        bias_f[gid] = v;
    } else if (b == 768) {
        for (int c = t; c < 1536; c += 256) {
            int head = c / 96, rem = c - head * 96;
            int which = rem >> 5, d = rem & 31;
            qkvb_r[c] = qkv_b[head * 96 + d * 3 + which];
        }
    } else {
        // x -> bf16 PADDED [131072][512], pre-swizzled by dest row&7.
        int gid = (b - 769) * 256 + t;      // < 1048576 = 131072*8
        int row = gid >> 3, kt = gid & 7;
        int win = row >> 6, tok = row & 63; if (tok > 48) tok = 48;
        int sw = row & 7;
        const float* src = x + ((size_t)win * 49 + tok) * 512 + kt * 64;
        unsigned short* dst = xs + (size_t)row * 512 + kt * 64;
#pragma unroll
        for (int c = 0; c < 8; ++c) {
            int cs = (c ^ sw) * 8;
            float f[8];
            *(float4*)&f[0] = *(const float4*)(src + cs);
            *(float4*)&f[4] = *(const float4*)(src + cs + 4);
            *(uint4*)(dst + c * 8) = cvt8(f);
        }
    }
}

// ================= K1: fused QKV GEMM + attention =================
// block = (mb: 2 windows, hp: 2 heads), 256 threads / 4 waves.
// Wave W: win = W&1 (rows (W&1)*64..+64), head = hp*2 + (W>>1)
//         (cols (W>>1)*96..+96 of the block's 192-col B panel).
// LDS (53248 B total, time-overlaid):
//  GEMM phase:  A stage [0,16384) = [128][128B swz]
//               B stage [16384,40960) = [192][128B swz]
//  post-GEMM:   qkv [0,53248) = 4 slots x {q[64][36],k[64][36],vt[32][64]}
//               P (8KB/wave) overlays wave's OWN slot's dead q+k (9216B)
__global__ __launch_bounds__(256, 3)
void qkvattn_kernel(const unsigned short* __restrict__ xs,
                    const unsigned short* __restrict__ wqkv_f,
                    const float* __restrict__ qkvb_r,
                    const float* __restrict__ bias_f,
                    unsigned short* __restrict__ attnout) {
    __shared__ __align__(16) char smem[53248];
    char* As = smem;
    char* Bs = smem + 16384;

    // XCD swizzle: 8192 blocks = 8 * 1024; (mb,hp) packed hp-inner.
    int i = blockIdx.x;
    int virt = (i & 7) * 1024 + (i >> 3);
    int mb = virt >> 3, hp = virt & 7;      // mb: 0..1023 (2 windows), hp: 0..7
    int m0 = mb * 128;

    const int tid = threadIdx.x;
    const int l = tid & 63;
    const int W = tid >> 6;
    const int lr = l & 15;
    const int lg = l >> 4;
    const int hs = W >> 1;                  // head-sub 0/1
    const int wl = W & 1;                   // window-sub 0/1
    const int head = hp * 2 + hs;

    f32x4 acc[4][6];
    const f32x4 zf = {0.f, 0.f, 0.f, 0.f};
#pragma unroll
    for (int mt = 0; mt < 4; ++mt)
#pragma unroll
        for (int nt = 0; nt < 6; ++nt) acc[mt][nt] = zf;

    int rsub = l >> 3, csub = l & 7;
    int cswz = (csub ^ rsub) * 16;         // B runtime inverse-swizzle
    int clin = csub * 16;                  // A linear (xs pre-swizzled)

    const char* bbase = (const char*)wqkv_f + (size_t)hp * 192 * 1024;
    const char* abase = (const char*)xs + ((size_t)m0 * 512) * 2;

#pragma unroll 1
    for (int kt = 0; kt < 8; ++kt) {
        int ko = kt * 128;                 // byte offset of k-tile (64 bf16)
        // A: 128 rows x 128B; 4 loads/thread
#pragma unroll
        for (int ii = 0; ii < 4; ++ii) {
            int r = ii * 32 + W * 8 + rsub;
            GLOAD16(abase + (size_t)r * 1024 + ko + clin, As + ii * 4096 + W * 1024);
        }
        // B: 192 rows x 128B; 6 loads/thread
#pragma unroll
        for (int jj = 0; jj < 6; ++jj) {
            int r = jj * 32 + W * 8 + rsub;
            GLOAD16(bbase + (size_t)r * 1024 + ko + cswz, Bs + jj * 4096 + W * 1024);
        }
        __syncthreads();
#pragma unroll
        for (int ks = 0; ks < 2; ++ks) {
            bf16x8 af[4], bf[6];
#pragma unroll
            for (int mt = 0; mt < 4; ++mt) {
                int row = wl * 64 + mt * 16 + lr;
                af[mt] = *(const bf16x8*)(As + row * 128 +
                    ((ks * 64 + lg * 16) ^ ((row & 7) << 4)));
            }
#pragma unroll
            for (int nt = 0; nt < 6; ++nt) {
                int row = hs * 96 + nt * 16 + lr;
                bf[nt] = *(const bf16x8*)(Bs + row * 128 +
                    ((ks * 64 + lg * 16) ^ ((row & 7) << 4)));
            }
#pragma unroll
            for (int mt = 0; mt < 4; ++mt)
#pragma unroll
                for (int nt = 0; nt < 6; ++nt)
                    acc[mt][nt] = __builtin_amdgcn_mfma_f32_16x16x32_bf16(
                        af[mt], bf[nt], acc[mt][nt], 0, 0, 0);
        }
        __syncthreads();
    }

    // ---- scatter acc -> qkv LDS (overlays dead A/B stage) ----
    // wave W owns slot W = (win wl, head): 64 toks x 96 cols, wave-local.
    unsigned short* wbuf = (unsigned short*)smem + W * WIN_ELEMS;
    {
        int tokb = 4 * lg;
#pragma unroll
        for (int nt = 0; nt < 6; ++nt) {
            const int which = nt >> 1;
            const int d = (nt & 1) * 16 + lr;
            float bias = qkvb_r[head * 96 + which * 32 + d];
            float sc = (which == 0) ? SCALE_Q : 1.0f;
#pragma unroll
            for (int mt = 0; mt < 4; ++mt) {
                int tok0 = tokb + mt * 16;
                if (which == 2) {
                    // vt[d][tok], tok-chunk XOR swizzle; 4 toks in one chunk
                    int idx = VT_OFF + d * 64 + (((tok0 >> 3) ^ (d & 7)) << 3) + (tok0 & 7);
                    ushort4 u;
                    u.x = bfc(acc[mt][nt][0] + bias);
                    u.y = bfc(acc[mt][nt][1] + bias);
                    u.z = bfc(acc[mt][nt][2] + bias);
                    u.w = bfc(acc[mt][nt][3] + bias);
                    *(ushort4*)(wbuf + idx) = u;
                } else {
#pragma unroll
                    for (int r = 0; r < 4; ++r)
                        wbuf[which * K_OFF + (tok0 + r) * QK_STRIDE + d] =
                            bfc((acc[mt][nt][r] + bias) * sc);
                }
            }
        }
    }
    // no barrier: attention below is entirely wave-local (wave = its slot)

    // ---- attention: wave W = (win wl, head), barrier-free ----
    {
        const unsigned short* qa = wbuf;
        char* P = smem + W * (WIN_ELEMS * 2);   // 8KB, overlays own dead q+k
        int win_g = mb * 2 + wl;
        unsigned short* ao = attnout + (size_t)win_g * (49 * 512);

        bf16x8 qf[4], kf[4], vf[2][2];
#pragma unroll
        for (int i2 = 0; i2 < 4; ++i2) {
            qf[i2] = *(const bf16x8*)(qa + (i2 * 16 + lr) * QK_STRIDE + lg * 8);
            kf[i2] = *(const bf16x8*)(qa + K_OFF + (i2 * 16 + lr) * QK_STRIDE + lg * 8);
        }
#pragma unroll
        for (int ks = 0; ks < 2; ++ks)
#pragma unroll
            for (int nt = 0; nt < 2; ++nt) {
                int d = nt * 16 + lr;
                vf[ks][nt] = *(const bf16x8*)(qa + VT_OFF + d * 64 +
                    (((ks * 4 + lg) ^ (d & 7)) << 3));
            }

        // S^T[kv][q]
        f32x4 s[4][4];
#pragma unroll
        for (int mt = 0; mt < 4; ++mt)
#pragma unroll
            for (int qt = 0; qt < 4; ++qt)
                s[mt][qt] = __builtin_amdgcn_mfma_f32_16x16x32_bf16(
                    kf[mt], qf[qt], zf, 0, 0, 0);
        // bias (kv pads = -1e30)
#pragma unroll
        for (int qt = 0; qt < 4; ++qt) {
            int q = qt * 16 + lr;
            const float* bb = bias_f + ((size_t)head * 64 + q) * 64;
#pragma unroll
            for (int mt = 0; mt < 4; ++mt) {
                float4 b4 = *(const float4*)(bb + mt * 16 + lg * 4);
                s[mt][qt][0] += b4.x; s[mt][qt][1] += b4.y;
                s[mt][qt][2] += b4.z; s[mt][qt][3] += b4.w;
            }
        }
        // softmax per q column; P -> LDS bf16 (overwrites own q/k — reads done)
#pragma unroll
        for (int qt = 0; qt < 4; ++qt) {
            float m = -1e30f;
#pragma unroll
            for (int mt = 0; mt < 4; ++mt)
#pragma unroll
                for (int r = 0; r < 4; ++r) m = fmaxf(m, s[mt][qt][r]);
            m = fmaxf(m, __shfl_xor(m, 16));
            m = fmaxf(m, __shfl_xor(m, 32));
            float sum = 0.f;
#pragma unroll
            for (int mt = 0; mt < 4; ++mt)
#pragma unroll
                for (int r = 0; r < 4; ++r) {
                    float p = __expf(s[mt][qt][r] - m);
                    s[mt][qt][r] = p; sum += p;
                }
            sum += __shfl_xor(sum, 16);
            sum += __shfl_xor(sum, 32);
            float inv = 1.0f / sum;
            int ql = qt * 16 + lr;          // 0..63
            int sw = (ql & 7) << 4;
#pragma unroll
            for (int mt = 0; mt < 4; ++mt) {
                uint2 uv;
                uv.x = (unsigned)bfc(s[mt][qt][0] * inv) |
                       ((unsigned)bfc(s[mt][qt][1] * inv) << 16);
                uv.y = (unsigned)bfc(s[mt][qt][2] * inv) |
                       ((unsigned)bfc(s[mt][qt][3] * inv) << 16);
                *(uint2*)(P + ql * 128 + ((mt * 32 + lg * 8) ^ sw)) = uv;
            }
        }
        // PV
        f32x4 o[4][2];
#pragma unroll
        for (int mt = 0; mt < 4; ++mt) {
            o[mt][0] = zf; o[mt][1] = zf;
            int ql = mt * 16 + lr;
            int sw = (ql & 7) << 4;
#pragma unroll
            for (int ks = 0; ks < 2; ++ks) {
                bf16x8 pf = *(const bf16x8*)(P + ql * 128 + ((ks * 64 + lg * 16) ^ sw));
                o[mt][0] = __builtin_amdgcn_mfma_f32_16x16x32_bf16(pf, vf[ks][0], o[mt][0], 0, 0, 0);
                o[mt][1] = __builtin_amdgcn_mfma_f32_16x16x32_bf16(pf, vf[ks][1], o[mt][1], 0, 0, 0);
            }
        }
#pragma unroll
        for (int mt = 0; mt < 4; ++mt)
#pragma unroll
            for (int nt = 0; nt < 2; ++nt)
#pragma unroll
                for (int r = 0; r < 4; ++r) {
                    int q = mt * 16 + 4 * lg + r;
                    if (q < 49)
                        ao[q * 512 + head * 32 + nt * 16 + lr] = bfc(o[mt][nt][r]);
                }
    }
}

// ================= K3: proj GEMM (unchanged, proven) =================
__global__ __launch_bounds__(256, 2)
void proj_kernel(const unsigned short* __restrict__ attnout,
                 const unsigned short* __restrict__ wproj_f,
                 const float* __restrict__ proj_b,
                 float* __restrict__ out) {
    __shared__ __align__(16) char smem[32768];
    char* As = smem;
    char* Bs = smem + 16384;

    int bid = blockIdx.x;
    int c = bid >> 2;
    int cs = (c & 7) * 98 + (c >> 3);
    int m0 = cs * 128;
    int n0 = (bid & 3) * 128;

    const int tid = threadIdx.x;
    const int l = tid & 63;
    const int W = tid >> 6;
    const int lr = l & 15;
    const int lg = l >> 4;
    const int Wm = W >> 1, Wn = W & 1;

    f32x4 acc[4][4];
    const f32x4 zf = {0.f, 0.f, 0.f, 0.f};
#pragma unroll
    for (int mt = 0; mt < 4; ++mt)
#pragma unroll
        for (int nt = 0; nt < 4; ++nt) acc[mt][nt] = zf;

    int rsub = l >> 3;
    int csub = l & 7;
    int cswz = (csub ^ rsub) * 16;

#pragma unroll 1
    for (int kt = 0; kt < 8; ++kt) {
#pragma unroll
        for (int i = 0; i < 4; ++i) {
            int r = i * 32 + W * 8 + rsub;
            const char* srcA = (const char*)attnout +
                ((size_t)(m0 + r) * 512 + kt * 64) * 2 + cswz;
            GLOAD16(srcA, As + i * 4096 + W * 1024);
            const char* srcB = (const char*)wproj_f +
                ((size_t)(n0 + r) * 512 + kt * 64) * 2 + cswz;
            GLOAD16(srcB, Bs + i * 4096 + W * 1024);
        }
        __syncthreads();
#pragma unroll
        for (int ks = 0; ks < 2; ++ks) {
            bf16x8 af[4], bf[4];
#pragma unroll
            for (int mt = 0; mt < 4; ++mt) {
                int row = Wm * 64 + mt * 16 + lr;
                af[mt] = *(const bf16x8*)(As + row * 128 +
                    ((ks * 64 + lg * 16) ^ ((row & 7) << 4)));
            }
#pragma unroll
            for (int nt = 0; nt < 4; ++nt) {
                int row = Wn * 64 + nt * 16 + lr;
                bf[nt] = *(const bf16x8*)(Bs + row * 128 +
                    ((ks * 64 + lg * 16) ^ ((row & 7) << 4)));
            }
#pragma unroll
            for (int mt = 0; mt < 4; ++mt)
#pragma unroll
                for (int nt = 0; nt < 4; ++nt)
                    acc[mt][nt] = __builtin_amdgcn_mfma_f32_16x16x32_bf16(
                        af[mt], bf[nt], acc[mt][nt], 0, 0, 0);
        }
        __syncthreads();
    }
#pragma unroll
    for (int nt = 0; nt < 4; ++nt) {
        int n = n0 + Wn * 64 + nt * 16 + lr;
        float pb = proj_b[n];
#pragma unroll
        for (int mt = 0; mt < 4; ++mt) {
#pragma unroll
            for (int r = 0; r < 4; ++r) {
                int m = m0 + Wm * 64 + mt * 16 + 4 * lg + r;
                out[(size_t)m * 512 + n] = acc[mt][nt][r] + pb;
            }
        }
    }
}

// =================== FALLBACK (round-2 path, proven) ===================
__global__ void prep2_kernel(const float* __restrict__ qkv_w,
                             const float* __restrict__ proj_w,
                             const float* __restrict__ bias_table,
                             unsigned short* __restrict__ wqkv_f,
                             unsigned short* __restrict__ wproj_f,
                             float* __restrict__ bias_f) {
    int b = blockIdx.x, t = threadIdx.x;
    if (b < 384) {
        int gid = b * 256 + t;
        int l = gid & 63; int r = gid >> 6;
        int dh = r & 1; r >>= 1;
        int ks = r & 15; r >>= 4;
        int h = r & 15; int which = r >> 4;
        int d = dh * 16 + (l & 15);
        int row = h * 96 + d * 3 + which;
        int c0 = ks * 32 + (l >> 4) * 8;
        const float* src = qkv_w + row * 512 + c0;
        unsigned short o[8];
#pragma unroll
        for (int j = 0; j < 8; ++j) o[j] = f2bf(src[j]);
        *(uint4*)(wqkv_f + (size_t)gid * 8) = pack8(o);
    } else if (b < 512) {
        int gid = (b - 384) * 256 + t;
        const float* src = proj_w + (size_t)gid * 8;
        unsigned short o[8];
#pragma unroll
        for (int j = 0; j < 8; ++j) o[j] = f2bf(src[j]);
        *(uint4*)(wproj_f + (size_t)gid * 8) = pack8(o);
    } else {
        int gid = (b - 512) * 256 + t;
        int j = gid & 63; int i = (gid >> 6) & 63; int h = gid >> 12;
        float v = -1e30f;
        if (i < 49 && j < 49) {
            int ri = i / 7, ci = i % 7, rj = j / 7, cj = j % 7;
            int idx = (ri - rj + 6) * 13 + (ci - cj + 6);
            v = bias_table[idx * 16 + h];
        }
        bias_f[gid] = v;
    }
}

__global__ __launch_bounds__(256, 2)
void attn_qkv_kernel(const float* __restrict__ x,
                     const float* __restrict__ qkv_b,
                     const unsigned short* __restrict__ wqkv_f,
                     const float* __restrict__ bias_f,
                     unsigned short* __restrict__ attnout) {
    __shared__ __align__(16) char smem[81920];
    const int tid = threadIdx.x;
    const int l = tid & 63;
    const int W = tid >> 6;
    const int lr = l & 15;
    const int lg = l >> 4;
    const int win = blockIdx.x;

    bf16x8 xf[16];
    {
        int trow = 16 * W + lr; if (trow > 48) trow = 48;
        const float* xr = x + ((size_t)win * 49 + trow) * 512;
#pragma unroll
        for (int ks = 0; ks < 16; ++ks) {
            float4 a = *(const float4*)(xr + ks * 32 + lg * 8);
            float4 b = *(const float4*)(xr + ks * 32 + lg * 8 + 4);
            BU8 u;
            u.s[0] = f2bf(a.x); u.s[1] = f2bf(a.y); u.s[2] = f2bf(a.z); u.s[3] = f2bf(a.w);
            u.s[4] = f2bf(b.x); u.s[5] = f2bf(b.y); u.s[6] = f2bf(b.z); u.s[7] = f2bf(b.w);
            xf[ks] = u.v;
        }
    }

    const f32x4 zf = {0.f, 0.f, 0.f, 0.f};
    unsigned short* ao = attnout + (size_t)win * (49 * 512);

    for (int hg = 0; hg < 4; ++hg) {
        for (int h2 = 0; h2 < 4; ++h2) {
            int h = hg * 4 + h2;
            char* qk = smem + h2 * 8192;
            char* vt = smem + 32768 + h2 * 4096;
#pragma unroll 1
            for (int which = 0; which < 3; ++which) {
                f32x4 a0 = zf, a1 = zf;
                const unsigned short* bp =
                    wqkv_f + (size_t)(which * 16 + h) * 16384 + l * 8;
#pragma unroll
                for (int ks = 0; ks < 16; ++ks) {
                    bf16x8 b0 = *(const bf16x8*)(bp + ks * 1024);
                    bf16x8 b1 = *(const bf16x8*)(bp + ks * 1024 + 512);
                    a0 = __builtin_amdgcn_mfma_f32_16x16x32_bf16(xf[ks], b0, a0, 0, 0, 0);
                    a1 = __builtin_amdgcn_mfma_f32_16x16x32_bf16(xf[ks], b1, a1, 0, 0, 0);
                }
                float bias0 = qkv_b[h * 96 + lr * 3 + which];
                float bias1 = qkv_b[h * 96 + (16 + lr) * 3 + which];
                if (which == 2) {
                    int d0 = lr, d1 = 16 + lr;
#pragma unroll
                    for (int r = 0; r < 4; ++r) {
                        int t = 16 * W + 4 * lg + r;
                        *(unsigned short*)(vt + d0 * 128 + ((t * 2) ^ ((d0 & 7) << 4))) =
                            f2bf(a0[r] + bias0);
                        *(unsigned short*)(vt + d1 * 128 + ((t * 2) ^ ((d1 & 7) << 4))) =
                            f2bf(a1[r] + bias1);
                    }
                } else {
                    float sc = (which == 0) ? SCALE_Q : 1.0f;
                    int cb = which * 64;
#pragma unroll
                    for (int r = 0; r < 4; ++r) {
                        int t = 16 * W + 4 * lg + r;
                        int sw = (t & 7) << 4;
                        *(unsigned short*)(qk + t * 128 + ((cb + lr * 2) ^ sw)) =
                            f2bf((a0[r] + bias0) * sc);
                        *(unsigned short*)(qk + t * 128 + ((cb + 32 + lr * 2) ^ sw)) =
                            f2bf((a1[r] + bias1) * sc);
                    }
                }
            }
        }
        __syncthreads();
        {
            int h = hg * 4 + W;
            char* qk = smem + W * 8192;
            char* vt = smem + 32768 + W * 4096;
            char* P  = smem + 49152 + W * 8192;

            bf16x8 kf[4], qf[4];
#pragma unroll
            for (int i = 0; i < 4; ++i) {
                int row = i * 16 + lr;
                int sw = (row & 7) << 4;
                qf[i] = *(const bf16x8*)(qk + row * 128 + ((lg * 16) ^ sw));
                kf[i] = *(const bf16x8*)(qk + row * 128 + ((64 + lg * 16) ^ sw));
            }
            f32x4 s[4][4];
#pragma unroll
            for (int mt = 0; mt < 4; ++mt)
#pragma unroll
                for (int qt = 0; qt < 4; ++qt)
                    s[mt][qt] = __builtin_amdgcn_mfma_f32_16x16x32_bf16(
                        kf[mt], qf[qt], zf, 0, 0, 0);
#pragma unroll
            for (int qt = 0; qt < 4; ++qt) {
                int q = qt * 16 + lr;
                const float* bb = bias_f + ((size_t)h * 64 + q) * 64;
#pragma unroll
                for (int mt = 0; mt < 4; ++mt) {
                    float4 b4 = *(const float4*)(bb + mt * 16 + lg * 4);
                    s[mt][qt][0] += b4.x; s[mt][qt][1] += b4.y;
                    s[mt][qt][2] += b4.z; s[mt][qt][3] += b4.w;
                }
            }
#pragma unroll
            for (int qt = 0; qt < 4; ++qt) {
                float m = -1e30f;
#pragma unroll
                for (int mt = 0; mt < 4; ++mt)
#pragma unroll
                    for (int r = 0; r < 4; ++r) m = fmaxf(m, s[mt][qt][r]);
                m = fmaxf(m, __shfl_xor(m, 16));
                m = fmaxf(m, __shfl_xor(m, 32));
                float sum = 0.f;
#pragma unroll
                for (int mt = 0; mt < 4; ++mt)
#pragma unroll
                    for (int r = 0; r < 4; ++r) {
                        float p = __expf(s[mt][qt][r] - m);
                        s[mt][qt][r] = p; sum += p;
                    }
                sum += __shfl_xor(sum, 16);
                sum += __shfl_xor(sum, 32);
                float inv = 1.0f / sum;
                int qrow = qt * 16 + lr;
                int sw = (qrow & 7) << 4;
#pragma unroll
                for (int mt = 0; mt < 4; ++mt) {
                    uint2 uv;
                    uv.x = (unsigned)f2bf(s[mt][qt][0] * inv) |
                           ((unsigned)f2bf(s[mt][qt][1] * inv) << 16);
                    uv.y = (unsigned)f2bf(s[mt][qt][2] * inv) |
                           ((unsigned)f2bf(s[mt][qt][3] * inv) << 16);
                    *(uint2*)(P + qrow * 128 + ((mt * 32 + lg * 8) ^ sw)) = uv;
                }
            }
            bf16x8 vf[2][2];
#pragma unroll
            for (int ks = 0; ks < 2; ++ks)
#pragma unroll
                for (int nt = 0; nt < 2; ++nt) {
                    int d = nt * 16 + lr;
                    vf[ks][nt] = *(const bf16x8*)(vt + d * 128 +
                        ((ks * 64 + lg * 16) ^ ((d & 7) << 4)));
                }
            f32x4 o[4][2];
#pragma unroll
            for (int mt = 0; mt < 4; ++mt) {
                o[mt][0] = zf; o[mt][1] = zf;
                int q = mt * 16 + lr;
                int sw = (q & 7) << 4;
#pragma unroll
                for (int ks = 0; ks < 2; ++ks) {
                    bf16x8 pf = *(const bf16x8*)(P + q * 128 + ((ks * 64 + lg * 16) ^ sw));
                    o[mt][0] = __builtin_amdgcn_mfma_f32_16x16x32_bf16(pf, vf[ks][0], o[mt][0], 0, 0, 0);
                    o[mt][1] = __builtin_amdgcn_mfma_f32_16x16x32_bf16(pf, vf[ks][1], o[mt][1], 0, 0, 0);
                }
            }
#pragma unroll
            for (int mt = 0; mt < 4; ++mt)
#pragma unroll
                for (int nt = 0; nt < 2; ++nt)
#pragma unroll
                    for (int r = 0; r < 4; ++r) {
                        int q = mt * 16 + 4 * lg + r;
                        if (q < 49)
                            ao[q * 512 + h * 32 + nt * 16 + lr] = f2bf(o[mt][nt][r]);
                    }
        }
        __syncthreads();
    }
}

extern "C" void kernel_launch(void* const* d_in, const int* in_sizes, int n_in,
                              void* d_out, int out_size, void* d_ws, size_t ws_size,
                              hipStream_t stream) {
    const float* x          = (const float*)d_in[0];
    const float* qkv_w      = (const float*)d_in[1];
    const float* qkv_b      = (const float*)d_in[2];
    const float* proj_w     = (const float*)d_in[3];
    const float* proj_b     = (const float*)d_in[4];
    const float* bias_table = (const float*)d_in[5];

    unsigned short* wqkv_f  = (unsigned short*)d_ws;
    unsigned short* wproj_f = wqkv_f + 786432;                 // @1.5MB
    float*          bias_f  = (float*)(wproj_f + 262144);      // @2.0MB

    if (ws_size >= WS2) {
        float* qkvb_r = (float*)((char*)d_ws + 2359296);
        unsigned short* xs      = (unsigned short*)((char*)d_ws + OFF_XS);
        unsigned short* attnout = (unsigned short*)((char*)d_ws + OFF_ATTN);
        hipLaunchKernelGGL(prepN_kernel, dim3(4865), dim3(256), 0, stream,
                           x, qkv_w, qkv_b, proj_w, bias_table,
                           wqkv_f, wproj_f, bias_f, qkvb_r, xs);
        hipLaunchKernelGGL(qkvattn_kernel, dim3(8192), dim3(256), 0, stream,
                           xs, wqkv_f, qkvb_r, bias_f, attnout);
        hipLaunchKernelGGL(proj_kernel, dim3(3136), dim3(256), 0, stream,
                           attnout, wproj_f, proj_b, (float*)d_out);
    } else if (ws_size >= WS_R2) {
        unsigned short* attnout = (unsigned short*)((char*)d_ws + 2359296);
        hipLaunchKernelGGL(prep2_kernel, dim3(768), dim3(256), 0, stream,
                           qkv_w, proj_w, bias_table, wqkv_f, wproj_f, bias_f);
        hipLaunchKernelGGL(attn_qkv_kernel, dim3(2048), dim3(256), 0, stream,
                           x, qkv_b, wqkv_f, bias_f, attnout);
        hipLaunchKernelGGL(proj_kernel, dim3(3136), dim3(256), 0, stream,
                           attnout, wproj_f, proj_b, (float*)d_out);
    }
}

// Round 16
// 438.720 us; speedup vs baseline: 1.2298x; 1.0637x over previous
//
#include <hip/hip_runtime.h>

// WindowAttention for MI355X (gfx950) — round 16.
// R15 host (best: 466us total) + COMPACT clamped xs:
//  xs is [100352][512] (no pad rows). global_load_lds's SOURCE addr is
//  per-lane, so the A-stage clamps tok=min(r&63,48) per lane and reads the
//  compact row (win*49+tok); LDS dest stays linear. Pre-swizzle key tok&7
//  == padded-row&7 for all real rows; clamped pad rows read permuted-but-
//  finite data (pad q discarded, pad k masked -1e30 -> P=0, pad v x 0).
//  Saves 31MB prep write + 23% xs cache footprint.
// Fallback: R2 path if ws too small.

typedef __bf16 bf16x8 __attribute__((ext_vector_type(8)));
typedef float f32x4 __attribute__((ext_vector_type(4)));

#define SCALE_Q 0.17677669529663687f

// ---- ws layout (bytes), new path ----
//  [0,        1572864)    wqkv_f  bf16 [1536][512], row c = head*96+which*32+d
//  [1572864,  2097152)    wproj_f bf16 [512][512] row-major
//  [2097152,  2359296)    bias_f  f32 [16][64][64], -1e30 pads
//  [2359296,  2365440)    qkvb_r  f32 [1536] reordered (head,which,d)
//  [2365440,  136583168)  xs      bf16 [100352][512] COMPACT, pre-swizzled
//  [136583168,239343616)  attnout bf16 [100352][512] compact
#define OFF_XS     2365440ull
#define OFF_ATTN   136583168ull
#define WS2        507779072ull
#define WS_R2      105119744ull

// qkv LDS geometry (elements): q[64][36] @0, k[64][36] @2304, vt[32][64] @4608
#define QK_STRIDE 36
#define K_OFF     2304
#define VT_OFF    4608
#define WIN_ELEMS 6656       // 13312 bytes per (win,head) slot

// native RNE f32->bf16 (compiler emits v_cvt_pk_bf16_f32 for pairs)
__device__ __forceinline__ unsigned short bfc(float f) {
    union { __bf16 b; unsigned short u; } x; x.b = (__bf16)f; return x.u;
}

__device__ __forceinline__ uint4 cvt8(const float f[8]) {
    uint4 p;
    p.x = (unsigned)bfc(f[0]) | ((unsigned)bfc(f[1]) << 16);
    p.y = (unsigned)bfc(f[2]) | ((unsigned)bfc(f[3]) << 16);
    p.z = (unsigned)bfc(f[4]) | ((unsigned)bfc(f[5]) << 16);
    p.w = (unsigned)bfc(f[6]) | ((unsigned)bfc(f[7]) << 16);
    return p;
}

__device__ __forceinline__ unsigned short f2bf(float f) {
    unsigned int u = __float_as_uint(f);
    u += 0x7FFFu + ((u >> 16) & 1u);
    return (unsigned short)(u >> 16);
}

__device__ __forceinline__ uint4 pack8(const unsigned short o[8]) {
    uint4 p;
    p.x = (unsigned)o[0] | ((unsigned)o[1] << 16);
    p.y = (unsigned)o[2] | ((unsigned)o[3] << 16);
    p.z = (unsigned)o[4] | ((unsigned)o[5] << 16);
    p.w = (unsigned)o[6] | ((unsigned)o[7] << 16);
    return p;
}

union BU8 { bf16x8 v; unsigned short s[8]; };

#define GLOAD16(g, l) __builtin_amdgcn_global_load_lds( \
    (__attribute__((address_space(1))) void*)(void*)(g), \
    (__attribute__((address_space(3))) void*)(l), 16, 0, 0)

// ================= prepN =================
__global__ void prepN_kernel(const float* __restrict__ x,
                             const float* __restrict__ qkv_w,
                             const float* __restrict__ qkv_b,
                             const float* __restrict__ proj_w,
                             const float* __restrict__ bias_table,
                             unsigned short* __restrict__ wqkv_f,
                             unsigned short* __restrict__ wproj_f,
                             float* __restrict__ bias_f,
                             float* __restrict__ qkvb_r,
                             unsigned short* __restrict__ xs) {
    int b = blockIdx.x, t = threadIdx.x;
    if (b < 384) {
        // wqkv_f[c][k], c = head*96 + which*32 + d  <-  qkv_w[head*96+d*3+which]
        int gid = b * 256 + t;              // 98304 = 1536*64
        int c = gid >> 6, k8 = (gid & 63) * 8;
        int head = c / 96, rem = c - head * 96;
        int which = rem >> 5, d = rem & 31;
        const float* src = qkv_w + (size_t)(head * 96 + d * 3 + which) * 512 + k8;
        float f[8];
#pragma unroll
        for (int j = 0; j < 8; ++j) f[j] = src[j];
        *(uint4*)(wqkv_f + (size_t)c * 512 + k8) = cvt8(f);
    } else if (b < 512) {
        int gid = (b - 384) * 256 + t;      // 32768 * 8 = 512*512
        const float* src = proj_w + (size_t)gid * 8;
        float f[8];
#pragma unroll
        for (int j = 0; j < 8; ++j) f[j] = src[j];
        *(uint4*)(wproj_f + (size_t)gid * 8) = cvt8(f);
    } else if (b < 768) {
        int gid = (b - 512) * 256 + t;      // 65536
        int j = gid & 63; int i = (gid >> 6) & 63; int h = gid >> 12;
        float v = -1e30f;
        if (i < 49 && j < 49) {
            int ri = i / 7, ci = i % 7, rj = j / 7, cj = j % 7;
            int idx = (ri - rj + 6) * 13 + (ci - cj + 6);
            v = bias_table[idx * 16 + h];
        }
        bias_f[gid] = v;
    } else if (b == 768) {
        for (int c = t; c < 1536; c += 256) {
            int head = c / 96, rem = c - head * 96;
            int which = rem >> 5, d = rem & 31;
            qkvb_r[c] = qkv_b[head * 96 + d * 3 + which];
        }
    } else {
        // x -> bf16 COMPACT [100352][512], pre-swizzled by (tok&7)
        // (tok&7 == padded-stage-row&7 for all real rows).
        int gid = (b - 769) * 256 + t;      // < 802816 = 100352*8
        int row = gid >> 3, kt = gid & 7;   // row = win*49 + tok
        int win = (int)(((unsigned long long)(unsigned)row * 87652394ull) >> 32);
        int tok = row - win * 49;
        int sw = tok & 7;
        const float* src = x + (size_t)row * 512 + kt * 64;
        unsigned short* dst = xs + (size_t)row * 512 + kt * 64;
#pragma unroll
        for (int c = 0; c < 8; ++c) {
            int cs = (c ^ sw) * 8;
            float f[8];
            *(float4*)&f[0] = *(const float4*)(src + cs);
            *(float4*)&f[4] = *(const float4*)(src + cs + 4);
            *(uint4*)(dst + c * 8) = cvt8(f);
        }
    }
}

// ================= K1: fused QKV GEMM + attention =================
// block = (mb: 2 windows, hp: 2 heads), 256 threads / 4 waves.
// Wave W: win = W&1 (rows (W&1)*64..+64), head = hp*2 + (W>>1).
// A source: compact xs with per-lane clamped row (srow = win*49+min(tok,48)).
// LDS (53248 B total, time-overlaid):
//  GEMM phase:  A stage [0,16384) = [128][128B swz]
//               B stage [16384,40960) = [192][128B swz]
//  post-GEMM:   qkv [0,53248) = 4 slots x {q[64][36],k[64][36],vt[32][64]}
//               P (8KB/wave) overlays wave's OWN slot's dead q+k (9216B)
__global__ __launch_bounds__(256, 3)
void qkvattn_kernel(const unsigned short* __restrict__ xs,
                    const unsigned short* __restrict__ wqkv_f,
                    const float* __restrict__ qkvb_r,
                    const float* __restrict__ bias_f,
                    unsigned short* __restrict__ attnout) {
    __shared__ __align__(16) char smem[53248];
    char* As = smem;
    char* Bs = smem + 16384;

    // XCD swizzle: 8192 blocks = 8 * 1024; (mb,hp) packed hp-inner.
    int i = blockIdx.x;
    int virt = (i & 7) * 1024 + (i >> 3);
    int mb = virt >> 3, hp = virt & 7;      // mb: 0..1023 (2 windows), hp: 0..7

    const int tid = threadIdx.x;
    const int l = tid & 63;
    const int W = tid >> 6;
    const int lr = l & 15;
    const int lg = l >> 4;
    const int hs = W >> 1;                  // head-sub 0/1
    const int wl = W & 1;                   // window-sub 0/1
    const int head = hp * 2 + hs;

    f32x4 acc[4][6];
    const f32x4 zf = {0.f, 0.f, 0.f, 0.f};
#pragma unroll
    for (int mt = 0; mt < 4; ++mt)
#pragma unroll
        for (int nt = 0; nt < 6; ++nt) acc[mt][nt] = zf;

    int rsub = l >> 3, csub = l & 7;
    int cswz = (csub ^ rsub) * 16;         // B runtime inverse-swizzle
    int clin = csub * 16;                  // A linear (xs pre-swizzled)

    const char* bbase = (const char*)wqkv_f + (size_t)hp * 192 * 1024;
    const char* xbase = (const char*)xs;

    // per-thread compact A source rows (clamped pads), constant across kt
    int asrow[4];
#pragma unroll
    for (int ii = 0; ii < 4; ++ii) {
        int r = ii * 32 + W * 8 + rsub;     // stage row 0..127
        int tok = r & 63; if (tok > 48) tok = 48;
        asrow[ii] = (mb * 2 + (r >> 6)) * 49 + tok;
    }

#pragma unroll 1
    for (int kt = 0; kt < 8; ++kt) {
        int ko = kt * 128;                 // byte offset of k-tile (64 bf16)
        // A: 128 stage rows x 128B; 4 loads/thread, compact clamped source
#pragma unroll
        for (int ii = 0; ii < 4; ++ii)
            GLOAD16(xbase + (size_t)asrow[ii] * 1024 + ko + clin,
                    As + ii * 4096 + W * 1024);
        // B: 192 rows x 128B; 6 loads/thread
#pragma unroll
        for (int jj = 0; jj < 6; ++jj) {
            int r = jj * 32 + W * 8 + rsub;
            GLOAD16(bbase + (size_t)r * 1024 + ko + cswz, Bs + jj * 4096 + W * 1024);
        }
        __syncthreads();
#pragma unroll
        for (int ks = 0; ks < 2; ++ks) {
            bf16x8 af[4], bf[6];
#pragma unroll
            for (int mt = 0; mt < 4; ++mt) {
                int row = wl * 64 + mt * 16 + lr;
                af[mt] = *(const bf16x8*)(As + row * 128 +
                    ((ks * 64 + lg * 16) ^ ((row & 7) << 4)));
            }
#pragma unroll
            for (int nt = 0; nt < 6; ++nt) {
                int row = hs * 96 + nt * 16 + lr;
                bf[nt] = *(const bf16x8*)(Bs + row * 128 +
                    ((ks * 64 + lg * 16) ^ ((row & 7) << 4)));
            }
#pragma unroll
            for (int mt = 0; mt < 4; ++mt)
#pragma unroll
                for (int nt = 0; nt < 6; ++nt)
                    acc[mt][nt] = __builtin_amdgcn_mfma_f32_16x16x32_bf16(
                        af[mt], bf[nt], acc[mt][nt], 0, 0, 0);
        }
        __syncthreads();
    }

    // ---- scatter acc -> qkv LDS (overlays dead A/B stage) ----
    // wave W owns slot W = (win wl, head): 64 toks x 96 cols, wave-local.
    unsigned short* wbuf = (unsigned short*)smem + W * WIN_ELEMS;
    {
        int tokb = 4 * lg;
#pragma unroll
        for (int nt = 0; nt < 6; ++nt) {
            const int which = nt >> 1;
            const int d = (nt & 1) * 16 + lr;
            float bias = qkvb_r[head * 96 + which * 32 + d];
            float sc = (which == 0) ? SCALE_Q : 1.0f;
#pragma unroll
            for (int mt = 0; mt < 4; ++mt) {
                int tok0 = tokb + mt * 16;
                if (which == 2) {
                    // vt[d][tok], tok-chunk XOR swizzle; 4 toks in one chunk
                    int idx = VT_OFF + d * 64 + (((tok0 >> 3) ^ (d & 7)) << 3) + (tok0 & 7);
                    ushort4 u;
                    u.x = bfc(acc[mt][nt][0] + bias);
                    u.y = bfc(acc[mt][nt][1] + bias);
                    u.z = bfc(acc[mt][nt][2] + bias);
                    u.w = bfc(acc[mt][nt][3] + bias);
                    *(ushort4*)(wbuf + idx) = u;
                } else {
#pragma unroll
                    for (int r = 0; r < 4; ++r)
                        wbuf[which * K_OFF + (tok0 + r) * QK_STRIDE + d] =
                            bfc((acc[mt][nt][r] + bias) * sc);
                }
            }
        }
    }
    // no barrier: attention below is entirely wave-local (wave = its slot)

    // ---- attention: wave W = (win wl, head), barrier-free ----
    {
        const unsigned short* qa = wbuf;
        char* P = smem + W * (WIN_ELEMS * 2);   // 8KB, overlays own dead q+k
        int win_g = mb * 2 + wl;
        unsigned short* ao = attnout + (size_t)win_g * (49 * 512);

        bf16x8 qf[4], kf[4], vf[2][2];
#pragma unroll
        for (int i2 = 0; i2 < 4; ++i2) {
            qf[i2] = *(const bf16x8*)(qa + (i2 * 16 + lr) * QK_STRIDE + lg * 8);
            kf[i2] = *(const bf16x8*)(qa + K_OFF + (i2 * 16 + lr) * QK_STRIDE + lg * 8);
        }
#pragma unroll
        for (int ks = 0; ks < 2; ++ks)
#pragma unroll
            for (int nt = 0; nt < 2; ++nt) {
                int d = nt * 16 + lr;
                vf[ks][nt] = *(const bf16x8*)(qa + VT_OFF + d * 64 +
                    (((ks * 4 + lg) ^ (d & 7)) << 3));
            }

        // S^T[kv][q]
        f32x4 s[4][4];
#pragma unroll
        for (int mt = 0; mt < 4; ++mt)
#pragma unroll
            for (int qt = 0; qt < 4; ++qt)
                s[mt][qt] = __builtin_amdgcn_mfma_f32_16x16x32_bf16(
                    kf[mt], qf[qt], zf, 0, 0, 0);
        // bias (kv pads = -1e30)
#pragma unroll
        for (int qt = 0; qt < 4; ++qt) {
            int q = qt * 16 + lr;
            const float* bb = bias_f + ((size_t)head * 64 + q) * 64;
#pragma unroll
            for (int mt = 0; mt < 4; ++mt) {
                float4 b4 = *(const float4*)(bb + mt * 16 + lg * 4);
                s[mt][qt][0] += b4.x; s[mt][qt][1] += b4.y;
                s[mt][qt][2] += b4.z; s[mt][qt][3] += b4.w;
            }
        }
        // softmax per q column; P -> LDS bf16 (overwrites own q/k — reads done)
#pragma unroll
        for (int qt = 0; qt < 4; ++qt) {
            float m = -1e30f;
#pragma unroll
            for (int mt = 0; mt < 4; ++mt)
#pragma unroll
                for (int r = 0; r < 4; ++r) m = fmaxf(m, s[mt][qt][r]);
            m = fmaxf(m, __shfl_xor(m, 16));
            m = fmaxf(m, __shfl_xor(m, 32));
            float sum = 0.f;
#pragma unroll
            for (int mt = 0; mt < 4; ++mt)
#pragma unroll
                for (int r = 0; r < 4; ++r) {
                    float p = __expf(s[mt][qt][r] - m);
                    s[mt][qt][r] = p; sum += p;
                }
            sum += __shfl_xor(sum, 16);
            sum += __shfl_xor(sum, 32);
            float inv = 1.0f / sum;
            int ql = qt * 16 + lr;          // 0..63
            int sw = (ql & 7) << 4;
#pragma unroll
            for (int mt = 0; mt < 4; ++mt) {
                uint2 uv;
                uv.x = (unsigned)bfc(s[mt][qt][0] * inv) |
                       ((unsigned)bfc(s[mt][qt][1] * inv) << 16);
                uv.y = (unsigned)bfc(s[mt][qt][2] * inv) |
                       ((unsigned)bfc(s[mt][qt][3] * inv) << 16);
                *(uint2*)(P + ql * 128 + ((mt * 32 + lg * 8) ^ sw)) = uv;
            }
        }
        // PV
        f32x4 o[4][2];
#pragma unroll
        for (int mt = 0; mt < 4; ++mt) {
            o[mt][0] = zf; o[mt][1] = zf;
            int ql = mt * 16 + lr;
            int sw = (ql & 7) << 4;
#pragma unroll
            for (int ks = 0; ks < 2; ++ks) {
                bf16x8 pf = *(const bf16x8*)(P + ql * 128 + ((ks * 64 + lg * 16) ^ sw));
                o[mt][0] = __builtin_amdgcn_mfma_f32_16x16x32_bf16(pf, vf[ks][0], o[mt][0], 0, 0, 0);
                o[mt][1] = __builtin_amdgcn_mfma_f32_16x16x32_bf16(pf, vf[ks][1], o[mt][1], 0, 0, 0);
            }
        }
#pragma unroll
        for (int mt = 0; mt < 4; ++mt)
#pragma unroll
            for (int nt = 0; nt < 2; ++nt)
#pragma unroll
                for (int r = 0; r < 4; ++r) {
                    int q = mt * 16 + 4 * lg + r;
                    if (q < 49)
                        ao[q * 512 + head * 32 + nt * 16 + lr] = bfc(o[mt][nt][r]);
                }
    }
}

// ================= K3: proj GEMM (unchanged, proven) =================
__global__ __launch_bounds__(256, 2)
void proj_kernel(const unsigned short* __restrict__ attnout,
                 const unsigned short* __restrict__ wproj_f,
                 const float* __restrict__ proj_b,
                 float* __restrict__ out) {
    __shared__ __align__(16) char smem[32768];
    char* As = smem;
    char* Bs = smem + 16384;

    int bid = blockIdx.x;
    int c = bid >> 2;
    int cs = (c & 7) * 98 + (c >> 3);
    int m0 = cs * 128;
    int n0 = (bid & 3) * 128;

    const int tid = threadIdx.x;
    const int l = tid & 63;
    const int W = tid >> 6;
    const int lr = l & 15;
    const int lg = l >> 4;
    const int Wm = W >> 1, Wn = W & 1;

    f32x4 acc[4][4];
    const f32x4 zf = {0.f, 0.f, 0.f, 0.f};
#pragma unroll
    for (int mt = 0; mt < 4; ++mt)
#pragma unroll
        for (int nt = 0; nt < 4; ++nt) acc[mt][nt] = zf;

    int rsub = l >> 3;
    int csub = l & 7;
    int cswz = (csub ^ rsub) * 16;

#pragma unroll 1
    for (int kt = 0; kt < 8; ++kt) {
#pragma unroll
        for (int i = 0; i < 4; ++i) {
            int r = i * 32 + W * 8 + rsub;
            const char* srcA = (const char*)attnout +
                ((size_t)(m0 + r) * 512 + kt * 64) * 2 + cswz;
            GLOAD16(srcA, As + i * 4096 + W * 1024);
            const char* srcB = (const char*)wproj_f +
                ((size_t)(n0 + r) * 512 + kt * 64) * 2 + cswz;
            GLOAD16(srcB, Bs + i * 4096 + W * 1024);
        }
        __syncthreads();
#pragma unroll
        for (int ks = 0; ks < 2; ++ks) {
            bf16x8 af[4], bf[4];
#pragma unroll
            for (int mt = 0; mt < 4; ++mt) {
                int row = Wm * 64 + mt * 16 + lr;
                af[mt] = *(const bf16x8*)(As + row * 128 +
                    ((ks * 64 + lg * 16) ^ ((row & 7) << 4)));
            }
#pragma unroll
            for (int nt = 0; nt < 4; ++nt) {
                int row = Wn * 64 + nt * 16 + lr;
                bf[nt] = *(const bf16x8*)(Bs + row * 128 +
                    ((ks * 64 + lg * 16) ^ ((row & 7) << 4)));
            }
#pragma unroll
            for (int mt = 0; mt < 4; ++mt)
#pragma unroll
                for (int nt = 0; nt < 4; ++nt)
                    acc[mt][nt] = __builtin_amdgcn_mfma_f32_16x16x32_bf16(
                        af[mt], bf[nt], acc[mt][nt], 0, 0, 0);
        }
        __syncthreads();
    }
#pragma unroll
    for (int nt = 0; nt < 4; ++nt) {
        int n = n0 + Wn * 64 + nt * 16 + lr;
        float pb = proj_b[n];
#pragma unroll
        for (int mt = 0; mt < 4; ++mt) {
#pragma unroll
            for (int r = 0; r < 4; ++r) {
                int m = m0 + Wm * 64 + mt * 16 + 4 * lg + r;
                out[(size_t)m * 512 + n] = acc[mt][nt][r] + pb;
            }
        }
    }
}

// =================== FALLBACK (round-2 path, proven) ===================
__global__ void prep2_kernel(const float* __restrict__ qkv_w,
                             const float* __restrict__ proj_w,
                             const float* __restrict__ bias_table,
                             unsigned short* __restrict__ wqkv_f,
                             unsigned short* __restrict__ wproj_f,
                             float* __restrict__ bias_f) {
    int b = blockIdx.x, t = threadIdx.x;
    if (b < 384) {
        int gid = b * 256 + t;
        int l = gid & 63; int r = gid >> 6;
        int dh = r & 1; r >>= 1;
        int ks = r & 15; r >>= 4;
        int h = r & 15; int which = r >> 4;
        int d = dh * 16 + (l & 15);
        int row = h * 96 + d * 3 + which;
        int c0 = ks * 32 + (l >> 4) * 8;
        const float* src = qkv_w + row * 512 + c0;
        unsigned short o[8];
#pragma unroll
        for (int j = 0; j < 8; ++j) o[j] = f2bf(src[j]);
        *(uint4*)(wqkv_f + (size_t)gid * 8) = pack8(o);
    } else if (b < 512) {
        int gid = (b - 384) * 256 + t;
        const float* src = proj_w + (size_t)gid * 8;
        unsigned short o[8];
#pragma unroll
        for (int j = 0; j < 8; ++j) o[j] = f2bf(src[j]);
        *(uint4*)(wproj_f + (size_t)gid * 8) = pack8(o);
    } else {
        int gid = (b - 512) * 256 + t;
        int j = gid & 63; int i = (gid >> 6) & 63; int h = gid >> 12;
        float v = -1e30f;
        if (i < 49 && j < 49) {
            int ri = i / 7, ci = i % 7, rj = j / 7, cj = j % 7;
            int idx = (ri - rj + 6) * 13 + (ci - cj + 6);
            v = bias_table[idx * 16 + h];
        }
        bias_f[gid] = v;
    }
}

__global__ __launch_bounds__(256, 2)
void attn_qkv_kernel(const float* __restrict__ x,
                     const float* __restrict__ qkv_b,
                     const unsigned short* __restrict__ wqkv_f,
                     const float* __restrict__ bias_f,
                     unsigned short* __restrict__ attnout) {
    __shared__ __align__(16) char smem[81920];
    const int tid = threadIdx.x;
    const int l = tid & 63;
    const int W = tid >> 6;
    const int lr = l & 15;
    const int lg = l >> 4;
    const int win = blockIdx.x;

    bf16x8 xf[16];
    {
        int trow = 16 * W + lr; if (trow > 48) trow = 48;
        const float* xr = x + ((size_t)win * 49 + trow) * 512;
#pragma unroll
        for (int ks = 0; ks < 16; ++ks) {
            float4 a = *(const float4*)(xr + ks * 32 + lg * 8);
            float4 b = *(const float4*)(xr + ks * 32 + lg * 8 + 4);
            BU8 u;
            u.s[0] = f2bf(a.x); u.s[1] = f2bf(a.y); u.s[2] = f2bf(a.z); u.s[3] = f2bf(a.w);
            u.s[4] = f2bf(b.x); u.s[5] = f2bf(b.y); u.s[6] = f2bf(b.z); u.s[7] = f2bf(b.w);
            xf[ks] = u.v;
        }
    }

    const f32x4 zf = {0.f, 0.f, 0.f, 0.f};
    unsigned short* ao = attnout + (size_t)win * (49 * 512);

    for (int hg = 0; hg < 4; ++hg) {
        for (int h2 = 0; h2 < 4; ++h2) {
            int h = hg * 4 + h2;
            char* qk = smem + h2 * 8192;
            char* vt = smem + 32768 + h2 * 4096;
#pragma unroll 1
            for (int which = 0; which < 3; ++which) {
                f32x4 a0 = zf, a1 = zf;
                const unsigned short* bp =
                    wqkv_f + (size_t)(which * 16 + h) * 16384 + l * 8;
#pragma unroll
                for (int ks = 0; ks < 16; ++ks) {
                    bf16x8 b0 = *(const bf16x8*)(bp + ks * 1024);
                    bf16x8 b1 = *(const bf16x8*)(bp + ks * 1024 + 512);
                    a0 = __builtin_amdgcn_mfma_f32_16x16x32_bf16(xf[ks], b0, a0, 0, 0, 0);
                    a1 = __builtin_amdgcn_mfma_f32_16x16x32_bf16(xf[ks], b1, a1, 0, 0, 0);
                }
                float bias0 = qkv_b[h * 96 + lr * 3 + which];
                float bias1 = qkv_b[h * 96 + (16 + lr) * 3 + which];
                if (which == 2) {
                    int d0 = lr, d1 = 16 + lr;
#pragma unroll
                    for (int r = 0; r < 4; ++r) {
                        int t = 16 * W + 4 * lg + r;
                        *(unsigned short*)(vt + d0 * 128 + ((t * 2) ^ ((d0 & 7) << 4))) =
                            f2bf(a0[r] + bias0);
                        *(unsigned short*)(vt + d1 * 128 + ((t * 2) ^ ((d1 & 7) << 4))) =
                            f2bf(a1[r] + bias1);
                    }
                } else {
                    float sc = (which == 0) ? SCALE_Q : 1.0f;
                    int cb = which * 64;
#pragma unroll
                    for (int r = 0; r < 4; ++r) {
                        int t = 16 * W + 4 * lg + r;
                        int sw = (t & 7) << 4;
                        *(unsigned short*)(qk + t * 128 + ((cb + lr * 2) ^ sw)) =
                            f2bf((a0[r] + bias0) * sc);
                        *(unsigned short*)(qk + t * 128 + ((cb + 32 + lr * 2) ^ sw)) =
                            f2bf((a1[r] + bias1) * sc);
                    }
                }
            }
        }
        __syncthreads();
        {
            int h = hg * 4 + W;
            char* qk = smem + W * 8192;
            char* vt = smem + 32768 + W * 4096;
            char* P  = smem + 49152 + W * 8192;

            bf16x8 kf[4], qf[4];
#pragma unroll
            for (int i = 0; i < 4; ++i) {
                int row = i * 16 + lr;
                int sw = (row & 7) << 4;
                qf[i] = *(const bf16x8*)(qk + row * 128 + ((lg * 16) ^ sw));
                kf[i] = *(const bf16x8*)(qk + row * 128 + ((64 + lg * 16) ^ sw));
            }
            f32x4 s[4][4];
#pragma unroll
            for (int mt = 0; mt < 4; ++mt)
#pragma unroll
                for (int qt = 0; qt < 4; ++qt)
                    s[mt][qt] = __builtin_amdgcn_mfma_f32_16x16x32_bf16(
                        kf[mt], qf[qt], zf, 0, 0, 0);
#pragma unroll
            for (int qt = 0; qt < 4; ++qt) {
                int q = qt * 16 + lr;
                const float* bb = bias_f + ((size_t)h * 64 + q) * 64;
#pragma unroll
                for (int mt = 0; mt < 4; ++mt) {
                    float4 b4 = *(const float4*)(bb + mt * 16 + lg * 4);
                    s[mt][qt][0] += b4.x; s[mt][qt][1] += b4.y;
                    s[mt][qt][2] += b4.z; s[mt][qt][3] += b4.w;
                }
            }
#pragma unroll
            for (int qt = 0; qt < 4; ++qt) {
                float m = -1e30f;
#pragma unroll
                for (int mt = 0; mt < 4; ++mt)
#pragma unroll
                    for (int r = 0; r < 4; ++r) m = fmaxf(m, s[mt][qt][r]);
                m = fmaxf(m, __shfl_xor(m, 16));
                m = fmaxf(m, __shfl_xor(m, 32));
                float sum = 0.f;
#pragma unroll
                for (int mt = 0; mt < 4; ++mt)
#pragma unroll
                    for (int r = 0; r < 4; ++r) {
                        float p = __expf(s[mt][qt][r] - m);
                        s[mt][qt][r] = p; sum += p;
                    }
                sum += __shfl_xor(sum, 16);
                sum += __shfl_xor(sum, 32);
                float inv = 1.0f / sum;
                int qrow = qt * 16 + lr;
                int sw = (qrow & 7) << 4;
#pragma unroll
                for (int mt = 0; mt < 4; ++mt) {
                    uint2 uv;
                    uv.x = (unsigned)f2bf(s[mt][qt][0] * inv) |
                           ((unsigned)f2bf(s[mt][qt][1] * inv) << 16);
                    uv.y = (unsigned)f2bf(s[mt][qt][2] * inv) |
                           ((unsigned)f2bf(s[mt][qt][3] * inv) << 16);
                    *(uint2*)(P + qrow * 128 + ((mt * 32 + lg * 8) ^ sw)) = uv;
                }
            }
            bf16x8 vf[2][2];
#pragma unroll
            for (int ks = 0; ks < 2; ++ks)
#pragma unroll
                for (int nt = 0; nt < 2; ++nt) {
                    int d = nt * 16 + lr;
                    vf[ks][nt] = *(const bf16x8*)(vt + d * 128 +
                        ((ks * 64 + lg * 16) ^ ((d & 7) << 4)));
                }
            f32x4 o[4][2];
#pragma unroll
            for (int mt = 0; mt < 4; ++mt) {
                o[mt][0] = zf; o[mt][1] = zf;
                int q = mt * 16 + lr;
                int sw = (q & 7) << 4;
#pragma unroll
                for (int ks = 0; ks < 2; ++ks) {
                    bf16x8 pf = *(const bf16x8*)(P + q * 128 + ((ks * 64 + lg * 16) ^ sw));
                    o[mt][0] = __builtin_amdgcn_mfma_f32_16x16x32_bf16(pf, vf[ks][0], o[mt][0], 0, 0, 0);
                    o[mt][1] = __builtin_amdgcn_mfma_f32_16x16x32_bf16(pf, vf[ks][1], o[mt][1], 0, 0, 0);
                }
            }
#pragma unroll
            for (int mt = 0; mt < 4; ++mt)
#pragma unroll
                for (int nt = 0; nt < 2; ++nt)
#pragma unroll
                    for (int r = 0; r < 4; ++r) {
                        int q = mt * 16 + 4 * lg + r;
                        if (q < 49)
                            ao[q * 512 + h * 32 + nt * 16 + lr] = f2bf(o[mt][nt][r]);
                    }
        }
        __syncthreads();
    }
}

extern "C" void kernel_launch(void* const* d_in, const int* in_sizes, int n_in,
                              void* d_out, int out_size, void* d_ws, size_t ws_size,
                              hipStream_t stream) {
    const float* x          = (const float*)d_in[0];
    const float* qkv_w      = (const float*)d_in[1];
    const float* qkv_b      = (const float*)d_in[2];
    const float* proj_w     = (const float*)d_in[3];
    const float* proj_b     = (const float*)d_in[4];
    const float* bias_table = (const float*)d_in[5];

    unsigned short* wqkv_f  = (unsigned short*)d_ws;
    unsigned short* wproj_f = wqkv_f + 786432;                 // @1.5MB
    float*          bias_f  = (float*)(wproj_f + 262144);      // @2.0MB

    if (ws_size >= WS2) {
        float* qkvb_r = (float*)((char*)d_ws + 2359296);
        unsigned short* xs      = (unsigned short*)((char*)d_ws + OFF_XS);
        unsigned short* attnout = (unsigned short*)((char*)d_ws + OFF_ATTN);
        hipLaunchKernelGGL(prepN_kernel, dim3(3905), dim3(256), 0, stream,
                           x, qkv_w, qkv_b, proj_w, bias_table,
                           wqkv_f, wproj_f, bias_f, qkvb_r, xs);
        hipLaunchKernelGGL(qkvattn_kernel, dim3(8192), dim3(256), 0, stream,
                           xs, wqkv_f, qkvb_r, bias_f, attnout);
        hipLaunchKernelGGL(proj_kernel, dim3(3136), dim3(256), 0, stream,
                           attnout, wproj_f, proj_b, (float*)d_out);
    } else if (ws_size >= WS_R2) {
        unsigned short* attnout = (unsigned short*)((char*)d_ws + 2359296);
        hipLaunchKernelGGL(prep2_kernel, dim3(768), dim3(256), 0, stream,
                           qkv_w, proj_w, bias_table, wqkv_f, wproj_f, bias_f);
        hipLaunchKernelGGL(attn_qkv_kernel, dim3(2048), dim3(256), 0, stream,
                           x, qkv_b, wqkv_f, bias_f, attnout);
        hipLaunchKernelGGL(proj_kernel, dim3(3136), dim3(256), 0, stream,
                           attnout, wproj_f, proj_b, (float*)d_out);
    }
}